// Round 1
// baseline (6261.784 us; speedup 1.0000x reference)
//
#include <hip/hip_runtime.h>
#include <cstdint>
#include <cstddef>

#define NNODES 50000
#define NEDGES 800000
#define HEADS 4
#define HID 64
#define FDIM 256          // HEADS*HID == IN_DIM == 256
#define NEG_SLOPE 0.2f

// ---------- helpers ----------
__device__ __forceinline__ unsigned enc_f32(float f) {
    unsigned u = __float_as_uint(f);
    return (u & 0x80000000u) ? ~u : (u | 0x80000000u);
}
__device__ __forceinline__ float dec_f32(unsigned u) {
    return (u & 0x80000000u) ? __uint_as_float(u & 0x7FFFFFFFu)
                             : __uint_as_float(~u);
}
__device__ __forceinline__ float elu_f(float x) {
    return x > 0.0f ? x : expm1f(x);
}
__device__ __forceinline__ float lrelu_f(float x) {
    return x > 0.0f ? x : NEG_SLOPE * x;
}

// ---------- GEMM: C[rows x 256] = A[rows x 256] @ W[256 x 256], fp32 ----------
// block = 256 threads, tile = 16 rows x 256 cols; each thread: 4 rows x 4 cols.
__global__ __launch_bounds__(256) void gemm256(const float* __restrict__ A,
                                               const float* __restrict__ W,
                                               float* __restrict__ C,
                                               int nrows) {
    __shared__ float sA[16][260];   // +4 pad
    const int tid = threadIdx.x;
    const int block_row = blockIdx.x * 16;

    // stage A tile: 16 rows x 256 cols = 1024 float4, 4 per thread
    #pragma unroll
    for (int i = 0; i < 4; ++i) {
        int f4 = tid + i * 256;          // 0..1023
        int r  = f4 >> 6;                // 64 float4 per row
        int c4 = f4 & 63;
        int gr = block_row + r;
        if (gr < nrows) {
            float4 v = *(const float4*)(A + (size_t)gr * FDIM + c4 * 4);
            *(float4*)(&sA[r][c4 * 4]) = v;
        }
    }
    __syncthreads();

    const int colg = (tid & 63) * 4;     // 0..252
    const int rowg = (tid >> 6) * 4;     // 0,4,8,12
    float4 acc0 = {0,0,0,0}, acc1 = {0,0,0,0}, acc2 = {0,0,0,0}, acc3 = {0,0,0,0};

    const float4* __restrict__ Wv = (const float4*)W;
    const int wcol = tid & 63;
    #pragma unroll 8
    for (int k = 0; k < 256; ++k) {
        float4 w = Wv[k * 64 + wcol];
        float a0 = sA[rowg + 0][k];
        float a1 = sA[rowg + 1][k];
        float a2 = sA[rowg + 2][k];
        float a3 = sA[rowg + 3][k];
        acc0.x += a0 * w.x; acc0.y += a0 * w.y; acc0.z += a0 * w.z; acc0.w += a0 * w.w;
        acc1.x += a1 * w.x; acc1.y += a1 * w.y; acc1.z += a1 * w.z; acc1.w += a1 * w.w;
        acc2.x += a2 * w.x; acc2.y += a2 * w.y; acc2.z += a2 * w.z; acc2.w += a2 * w.w;
        acc3.x += a3 * w.x; acc3.y += a3 * w.y; acc3.z += a3 * w.z; acc3.w += a3 * w.w;
    }

    int r0 = block_row + rowg;
    if (r0 + 3 < nrows) {
        *(float4*)(C + (size_t)(r0 + 0) * FDIM + colg) = acc0;
        *(float4*)(C + (size_t)(r0 + 1) * FDIM + colg) = acc1;
        *(float4*)(C + (size_t)(r0 + 2) * FDIM + colg) = acc2;
        *(float4*)(C + (size_t)(r0 + 3) * FDIM + colg) = acc3;
    }
}

// ---------- el/er: one wave per node ----------
__global__ __launch_bounds__(256) void elr_kernel(const float* __restrict__ feat,
                                                  const float* __restrict__ al,
                                                  const float* __restrict__ ar,
                                                  float* __restrict__ el,
                                                  float* __restrict__ er) {
    int gid  = blockIdx.x * blockDim.x + threadIdx.x;
    int node = gid >> 6;
    int lane = gid & 63;
    if (node >= NNODES) return;
    float4 f = *(const float4*)(feat + (size_t)node * FDIM + lane * 4);
    float4 a = ((const float4*)al)[lane];
    float4 b = ((const float4*)ar)[lane];
    float pl = f.x * a.x + f.y * a.y + f.z * a.z + f.w * a.w;
    float pr = f.x * b.x + f.y * b.y + f.z * b.z + f.w * b.w;
    #pragma unroll
    for (int off = 1; off < 16; off <<= 1) {
        pl += __shfl_xor(pl, off, 64);
        pr += __shfl_xor(pr, off, 64);
    }
    if ((lane & 15) == 0) {
        int h = lane >> 4;
        el[node * HEADS + h] = pl;
        er[node * HEADS + h] = pr;
    }
}

// ---------- per-edge scores + segment-max via encoded atomicMax ----------
__global__ __launch_bounds__(256) void scores_kernel(const int* __restrict__ src,
                                                     const int* __restrict__ dst,
                                                     const float* __restrict__ el,
                                                     const float* __restrict__ er,
                                                     float* __restrict__ ebuf,
                                                     unsigned* __restrict__ menc) {
    int e = blockIdx.x * blockDim.x + threadIdx.x;
    if (e >= NEDGES) return;
    int s = src[e], d = dst[e];
    float4 l = ((const float4*)el)[s];
    float4 r = ((const float4*)er)[d];
    float4 v;
    v.x = lrelu_f(l.x + r.x);
    v.y = lrelu_f(l.y + r.y);
    v.z = lrelu_f(l.z + r.z);
    v.w = lrelu_f(l.w + r.w);
    ((float4*)ebuf)[e] = v;
    unsigned* mp = menc + (size_t)d * HEADS;
    atomicMax(mp + 0, enc_f32(v.x));
    atomicMax(mp + 1, enc_f32(v.y));
    atomicMax(mp + 2, enc_f32(v.z));
    atomicMax(mp + 3, enc_f32(v.w));
}

// ---------- exp(e - m) + segment-sum ----------
__global__ __launch_bounds__(256) void expsum_kernel(const int* __restrict__ dst,
                                                     float* __restrict__ ebuf,
                                                     const unsigned* __restrict__ menc,
                                                     float* __restrict__ denom) {
    int e = blockIdx.x * blockDim.x + threadIdx.x;
    if (e >= NEDGES) return;
    int d = dst[e];
    float4 v = ((const float4*)ebuf)[e];
    uint4 mu = ((const uint4*)menc)[d];
    float4 p;
    p.x = expf(v.x - dec_f32(mu.x));
    p.y = expf(v.y - dec_f32(mu.y));
    p.z = expf(v.z - dec_f32(mu.z));
    p.w = expf(v.w - dec_f32(mu.w));
    ((float4*)ebuf)[e] = p;
    float* dp = denom + (size_t)d * HEADS;
    atomicAdd(dp + 0, p.x);
    atomicAdd(dp + 1, p.y);
    atomicAdd(dp + 2, p.z);
    atomicAdd(dp + 3, p.w);
}

// ---------- aggregation: 64 lanes per edge, atomicAdd into accumulator ----------
// LAYER==1: accum layout [node][256]; LAYER==2: accum layout [head][node][64]
template <int LAYER>
__global__ __launch_bounds__(256) void aggregate_kernel(const int* __restrict__ src,
                                                        const int* __restrict__ dst,
                                                        const float* __restrict__ ebuf,
                                                        const float* __restrict__ denom,
                                                        const float* __restrict__ feat,
                                                        float* __restrict__ accum) {
    int e = blockIdx.x * 4 + (threadIdx.x >> 6);
    if (e >= NEDGES) return;
    int lane = threadIdx.x & 63;
    int s = src[e], d = dst[e];
    int h = lane >> 4;
    float p  = ebuf[(size_t)e * HEADS + h];
    float dn = denom[(size_t)d * HEADS + h];
    float alpha = p / dn;
    float4 f = *(const float4*)(feat + (size_t)s * FDIM + lane * 4);
    float* op;
    if (LAYER == 1) {
        op = accum + (size_t)d * FDIM + lane * 4;
    } else {
        op = accum + ((size_t)h * NNODES + d) * HID + (lane & 15) * 4;
    }
    atomicAdd(op + 0, f.x * alpha);
    atomicAdd(op + 1, f.y * alpha);
    atomicAdd(op + 2, f.z * alpha);
    atomicAdd(op + 3, f.w * alpha);
}

// ---------- finalize: bias + ELU ----------
__global__ __launch_bounds__(256) void finalize1_kernel(float* __restrict__ acc,
                                                        const float* __restrict__ bias) {
    int i = blockIdx.x * blockDim.x + threadIdx.x;   // float4 index
    if (i >= NNODES * FDIM / 4) return;
    float4 v = ((float4*)acc)[i];
    float4 b = ((const float4*)bias)[i & 63];
    v.x = elu_f(v.x + b.x);
    v.y = elu_f(v.y + b.y);
    v.z = elu_f(v.z + b.z);
    v.w = elu_f(v.w + b.w);
    ((float4*)acc)[i] = v;
}

__global__ __launch_bounds__(256) void finalize2_kernel(float* __restrict__ out,
                                                        const float* __restrict__ bias) {
    int i = blockIdx.x * blockDim.x + threadIdx.x;   // float4 index over [H][N][16]
    if (i >= NNODES * FDIM / 4) return;
    int h  = i / (NNODES * (HID / 4));
    int d4 = i & 15;
    float4 v = ((float4*)out)[i];
    float4 b = ((const float4*)bias)[h * 16 + d4];
    v.x = elu_f(v.x + b.x);
    v.y = elu_f(v.y + b.y);
    v.z = elu_f(v.z + b.z);
    v.w = elu_f(v.w + b.w);
    ((float4*)out)[i] = v;
}

// ---------- launch ----------
extern "C" void kernel_launch(void* const* d_in, const int* in_sizes, int n_in,
                              void* d_out, int out_size, void* d_ws, size_t ws_size,
                              hipStream_t stream) {
    const float* x   = (const float*)d_in[0];
    const int*   src = (const int*)d_in[1];
    const int*   dst = (const int*)d_in[2];
    const float* W1  = (const float*)d_in[3];
    const float* al1 = (const float*)d_in[4];
    const float* ar1 = (const float*)d_in[5];
    const float* b1  = (const float*)d_in[6];
    const float* W2  = (const float*)d_in[7];
    const float* al2 = (const float*)d_in[8];
    const float* ar2 = (const float*)d_in[9];
    const float* b2  = (const float*)d_in[10];
    float* out = (float*)d_out;

    float* ws = (float*)d_ws;
    float*    feat  = ws;                                   // 12.8M f32
    float*    h1    = ws + (size_t)NNODES * FDIM;           // 12.8M f32
    float*    el    = h1 + (size_t)NNODES * FDIM;           // 200k
    float*    er    = el + (size_t)NNODES * HEADS;          // 200k
    unsigned* menc  = (unsigned*)(er + (size_t)NNODES * HEADS);   // 200k
    float*    denom = (float*)(menc + (size_t)NNODES * HEADS);    // 200k
    float*    ebuf  = denom + (size_t)NNODES * HEADS;       // 3.2M

    const int gemm_grid  = (NNODES + 15) / 16;        // 3125
    const int elr_grid   = (NNODES * 64) / 256;       // 12500
    const int edge_grid  = (NEDGES + 255) / 256;      // 3125
    const int agg_grid   = (NEDGES + 3) / 4;          // 200000
    const int fin_grid   = (NNODES * FDIM / 4) / 256; // 12500

    // ===== layer 1 =====
    hipMemsetAsync(h1,    0, (size_t)NNODES * FDIM * 4, stream);
    hipMemsetAsync(menc,  0, (size_t)NNODES * HEADS * 4, stream);
    hipMemsetAsync(denom, 0, (size_t)NNODES * HEADS * 4, stream);

    gemm256<<<gemm_grid, 256, 0, stream>>>(x, W1, feat, NNODES);
    elr_kernel<<<elr_grid, 256, 0, stream>>>(feat, al1, ar1, el, er);
    scores_kernel<<<edge_grid, 256, 0, stream>>>(src, dst, el, er, ebuf, menc);
    expsum_kernel<<<edge_grid, 256, 0, stream>>>(dst, ebuf, menc, denom);
    aggregate_kernel<1><<<agg_grid, 256, 0, stream>>>(src, dst, ebuf, denom, feat, h1);
    finalize1_kernel<<<fin_grid, 256, 0, stream>>>(h1, b1);

    // ===== layer 2 =====
    hipMemsetAsync(out,   0, (size_t)NNODES * FDIM * 4, stream);
    hipMemsetAsync(menc,  0, (size_t)NNODES * HEADS * 4, stream);
    hipMemsetAsync(denom, 0, (size_t)NNODES * HEADS * 4, stream);

    gemm256<<<gemm_grid, 256, 0, stream>>>(h1, W2, feat, NNODES);
    elr_kernel<<<elr_grid, 256, 0, stream>>>(feat, al2, ar2, el, er);
    scores_kernel<<<edge_grid, 256, 0, stream>>>(src, dst, el, er, ebuf, menc);
    expsum_kernel<<<edge_grid, 256, 0, stream>>>(dst, ebuf, menc, denom);
    aggregate_kernel<2><<<agg_grid, 256, 0, stream>>>(src, dst, ebuf, denom, feat, out);
    finalize2_kernel<<<fin_grid, 256, 0, stream>>>(out, b2);
}

// Round 2
// 598.350 us; speedup vs baseline: 10.4651x; 10.4651x over previous
//
#include <hip/hip_runtime.h>
#include <cstdint>
#include <cstddef>

#define NNODES 50000
#define NEDGES 800000
#define HEADS 4
#define HID 64
#define FDIM 256          // HEADS*HID == IN_DIM == 256
#define NEG_SLOPE 0.2f

// ---------- helpers ----------
__device__ __forceinline__ float elu_f(float x) {
    return x > 0.0f ? x : expm1f(x);
}
__device__ __forceinline__ float lrelu_f(float x) {
    return x > 0.0f ? x : NEG_SLOPE * x;
}

// ---------- GEMM: C[rows x 256] = A[rows x 256] @ W[256 x 256], fp32 ----------
__global__ __launch_bounds__(256) void gemm256(const float* __restrict__ A,
                                               const float* __restrict__ W,
                                               float* __restrict__ C,
                                               int nrows) {
    __shared__ float sA[16][260];   // +4 pad
    const int tid = threadIdx.x;
    const int block_row = blockIdx.x * 16;

    #pragma unroll
    for (int i = 0; i < 4; ++i) {
        int f4 = tid + i * 256;          // 0..1023
        int r  = f4 >> 6;                // 64 float4 per row
        int c4 = f4 & 63;
        int gr = block_row + r;
        if (gr < nrows) {
            float4 v = *(const float4*)(A + (size_t)gr * FDIM + c4 * 4);
            *(float4*)(&sA[r][c4 * 4]) = v;
        }
    }
    __syncthreads();

    const int colg = (tid & 63) * 4;     // 0..252
    const int rowg = (tid >> 6) * 4;     // 0,4,8,12
    float4 acc0 = {0,0,0,0}, acc1 = {0,0,0,0}, acc2 = {0,0,0,0}, acc3 = {0,0,0,0};

    const float4* __restrict__ Wv = (const float4*)W;
    const int wcol = tid & 63;
    #pragma unroll 8
    for (int k = 0; k < 256; ++k) {
        float4 w = Wv[k * 64 + wcol];
        float a0 = sA[rowg + 0][k];
        float a1 = sA[rowg + 1][k];
        float a2 = sA[rowg + 2][k];
        float a3 = sA[rowg + 3][k];
        acc0.x += a0 * w.x; acc0.y += a0 * w.y; acc0.z += a0 * w.z; acc0.w += a0 * w.w;
        acc1.x += a1 * w.x; acc1.y += a1 * w.y; acc1.z += a1 * w.z; acc1.w += a1 * w.w;
        acc2.x += a2 * w.x; acc2.y += a2 * w.y; acc2.z += a2 * w.z; acc2.w += a2 * w.w;
        acc3.x += a3 * w.x; acc3.y += a3 * w.y; acc3.z += a3 * w.z; acc3.w += a3 * w.w;
    }

    int r0 = block_row + rowg;
    if (r0 + 3 < nrows) {
        *(float4*)(C + (size_t)(r0 + 0) * FDIM + colg) = acc0;
        *(float4*)(C + (size_t)(r0 + 1) * FDIM + colg) = acc1;
        *(float4*)(C + (size_t)(r0 + 2) * FDIM + colg) = acc2;
        *(float4*)(C + (size_t)(r0 + 3) * FDIM + colg) = acc3;
    }
}

// ---------- el/er: one wave per node ----------
__global__ __launch_bounds__(256) void elr_kernel(const float* __restrict__ feat,
                                                  const float* __restrict__ al,
                                                  const float* __restrict__ ar,
                                                  float* __restrict__ el,
                                                  float* __restrict__ er) {
    int gid  = blockIdx.x * blockDim.x + threadIdx.x;
    int node = gid >> 6;
    int lane = gid & 63;
    if (node >= NNODES) return;
    float4 f = *(const float4*)(feat + (size_t)node * FDIM + lane * 4);
    float4 a = ((const float4*)al)[lane];
    float4 b = ((const float4*)ar)[lane];
    float pl = f.x * a.x + f.y * a.y + f.z * a.z + f.w * a.w;
    float pr = f.x * b.x + f.y * b.y + f.z * b.z + f.w * b.w;
    #pragma unroll
    for (int off = 1; off < 16; off <<= 1) {
        pl += __shfl_xor(pl, off, 64);
        pr += __shfl_xor(pr, off, 64);
    }
    if ((lane & 15) == 0) {
        int h = lane >> 4;
        el[node * HEADS + h] = pl;
        er[node * HEADS + h] = pr;
    }
}

// ---------- CSR build ----------
__global__ __launch_bounds__(256) void count_deg(const int* __restrict__ dst,
                                                 int* __restrict__ deg) {
    int e = blockIdx.x * 256 + threadIdx.x;
    if (e < NEDGES) atomicAdd(&deg[dst[e]], 1);
}

// inclusive scan of `in[0..n)` in 256-element blocks; bsums gets block totals
__global__ __launch_bounds__(256) void scan_block(const int* __restrict__ in,
                                                  int* __restrict__ out,
                                                  int* __restrict__ bsums, int n) {
    int gid = blockIdx.x * 256 + threadIdx.x;
    int v = (gid < n) ? in[gid] : 0;
    int lane = threadIdx.x & 63;
    #pragma unroll
    for (int off = 1; off < 64; off <<= 1) {
        int t = __shfl_up(v, off, 64);
        if (lane >= off) v += t;
    }
    __shared__ int wsum[4];
    int wid = threadIdx.x >> 6;
    if (lane == 63) wsum[wid] = v;
    __syncthreads();
    int add = 0;
    for (int w = 0; w < wid; ++w) add += wsum[w];
    v += add;
    if (gid < n) out[gid] = v;
    if (bsums && threadIdx.x == 255) bsums[blockIdx.x] = v;
}

__global__ __launch_bounds__(256) void scan_add(int* __restrict__ out,
                                                const int* __restrict__ bscan, int n) {
    int gid = blockIdx.x * 256 + threadIdx.x;
    if (blockIdx.x > 0 && gid < n) out[gid] += bscan[blockIdx.x - 1];
}

__global__ __launch_bounds__(256) void fill_csr(const int* __restrict__ src,
                                                const int* __restrict__ dst,
                                                const int* __restrict__ incl,
                                                const int* __restrict__ deg,
                                                int* __restrict__ cursor,
                                                int* __restrict__ csr_src) {
    int e = blockIdx.x * 256 + threadIdx.x;
    if (e >= NEDGES) return;
    int s = src[e], d = dst[e];
    int start = incl[d] - deg[d];
    int pos = start + atomicAdd(&cursor[d], 1);
    csr_src[pos] = s;
}

// ---------- fused per-node softmax + aggregate + bias + ELU ----------
// one 64-lane wave per dst node; 4 waves per block.
// LAYER==1: outp layout [node][256]; LAYER==2: outp layout [head][node][64]
template <int LAYER>
__global__ __launch_bounds__(256) void gat_node(const int* __restrict__ csr_src,
                                                const int* __restrict__ incl,
                                                const int* __restrict__ deg,
                                                const float* __restrict__ el,
                                                const float* __restrict__ er,
                                                const float* __restrict__ feat,
                                                const float* __restrict__ bias,
                                                float* __restrict__ outp) {
    int node = blockIdx.x * 4 + (threadIdx.x >> 6);
    if (node >= NNODES) return;
    int lane = threadIdx.x & 63;
    int h = lane >> 4;

    int end = incl[node];
    int dg = deg[node];
    int start = end - dg;

    float4 r4 = ((const float4*)er)[node];

    // pass A: per-head max over incoming edges (lane-strided)
    float m0 = -INFINITY, m1 = -INFINITY, m2 = -INFINITY, m3 = -INFINITY;
    for (int i = start + lane; i < end; i += 64) {
        int s = csr_src[i];
        float4 l4 = ((const float4*)el)[s];
        m0 = fmaxf(m0, lrelu_f(l4.x + r4.x));
        m1 = fmaxf(m1, lrelu_f(l4.y + r4.y));
        m2 = fmaxf(m2, lrelu_f(l4.z + r4.z));
        m3 = fmaxf(m3, lrelu_f(l4.w + r4.w));
    }
    #pragma unroll
    for (int off = 1; off < 64; off <<= 1) {
        m0 = fmaxf(m0, __shfl_xor(m0, off, 64));
        m1 = fmaxf(m1, __shfl_xor(m1, off, 64));
        m2 = fmaxf(m2, __shfl_xor(m2, off, 64));
        m3 = fmaxf(m3, __shfl_xor(m3, off, 64));
    }

    // pass B: softmax denominator per head
    float s0 = 0, s1 = 0, s2 = 0, s3 = 0;
    for (int i = start + lane; i < end; i += 64) {
        int s = csr_src[i];
        float4 l4 = ((const float4*)el)[s];
        s0 += expf(lrelu_f(l4.x + r4.x) - m0);
        s1 += expf(lrelu_f(l4.y + r4.y) - m1);
        s2 += expf(lrelu_f(l4.z + r4.z) - m2);
        s3 += expf(lrelu_f(l4.w + r4.w) - m3);
    }
    #pragma unroll
    for (int off = 1; off < 64; off <<= 1) {
        s0 += __shfl_xor(s0, off, 64);
        s1 += __shfl_xor(s1, off, 64);
        s2 += __shfl_xor(s2, off, 64);
        s3 += __shfl_xor(s3, off, 64);
    }

    float m_h     = (h == 0) ? m0 : (h == 1) ? m1 : (h == 2) ? m2 : m3;
    float den_h   = (h == 0) ? s0 : (h == 1) ? s1 : (h == 2) ? s2 : s3;
    float er_h    = (h == 0) ? r4.x : (h == 1) ? r4.y : (h == 2) ? r4.z : r4.w;
    float inv_den = 1.0f / den_h;

    // pass C: gather-aggregate. chunk srcs into registers, broadcast via shfl.
    float4 acc = {0, 0, 0, 0};
    for (int base = start; base < end; base += 64) {
        int cnt = min(64, end - base);
        int sp = (base + lane < end) ? csr_src[base + lane] : 0;
        for (int j = 0; j < cnt; ++j) {
            int s = __shfl(sp, j, 64);
            float sc = lrelu_f(el[s * HEADS + h] + er_h);
            float alpha = expf(sc - m_h) * inv_den;
            float4 f = *(const float4*)(feat + (size_t)s * FDIM + lane * 4);
            acc.x += f.x * alpha;
            acc.y += f.y * alpha;
            acc.z += f.z * alpha;
            acc.w += f.w * alpha;
        }
    }

    // epilogue: bias + ELU, single write
    float4 b = ((const float4*)bias)[lane];
    acc.x = elu_f(acc.x + b.x);
    acc.y = elu_f(acc.y + b.y);
    acc.z = elu_f(acc.z + b.z);
    acc.w = elu_f(acc.w + b.w);

    if (LAYER == 1) {
        *(float4*)(outp + (size_t)node * FDIM + lane * 4) = acc;
    } else {
        *(float4*)(outp + ((size_t)h * NNODES + node) * HID + (lane & 15) * 4) = acc;
    }
}

// ---------- launch ----------
extern "C" void kernel_launch(void* const* d_in, const int* in_sizes, int n_in,
                              void* d_out, int out_size, void* d_ws, size_t ws_size,
                              hipStream_t stream) {
    const float* x   = (const float*)d_in[0];
    const int*   src = (const int*)d_in[1];
    const int*   dst = (const int*)d_in[2];
    const float* W1  = (const float*)d_in[3];
    const float* al1 = (const float*)d_in[4];
    const float* ar1 = (const float*)d_in[5];
    const float* b1  = (const float*)d_in[6];
    const float* W2  = (const float*)d_in[7];
    const float* al2 = (const float*)d_in[8];
    const float* ar2 = (const float*)d_in[9];
    const float* b2  = (const float*)d_in[10];
    float* out = (float*)d_out;

    float* ws = (float*)d_ws;
    float* feat = ws;                                   // 12.8M f32
    float* h1   = feat + (size_t)NNODES * FDIM;         // 12.8M f32
    float* el   = h1 + (size_t)NNODES * FDIM;           // 200k
    float* er   = el + (size_t)NNODES * HEADS;          // 200k
    int* deg     = (int*)(er + (size_t)NNODES * HEADS); // 50k
    int* incl    = deg + NNODES;                        // 50k
    int* cursor  = incl + NNODES;                       // 50k
    int* aux     = cursor + NNODES;                     // 256
    int* auxs    = aux + 256;                           // 256
    int* csr_src = auxs + 256;                          // 800k

    const int gemm_grid  = (NNODES + 15) / 16;          // 3125
    const int elr_grid   = (NNODES * 64) / 256;         // 12500
    const int edge_grid  = (NEDGES + 255) / 256;        // 3125
    const int node_grid  = (NNODES + 255) / 256;        // 196
    const int gat_grid   = (NNODES + 3) / 4;            // 12500

    // ===== CSR build (shared by both layers) =====
    hipMemsetAsync(deg,    0, NNODES * sizeof(int), stream);
    hipMemsetAsync(cursor, 0, NNODES * sizeof(int), stream);
    count_deg<<<edge_grid, 256, 0, stream>>>(dst, deg);
    scan_block<<<node_grid, 256, 0, stream>>>(deg, incl, aux, NNODES);
    scan_block<<<1, 256, 0, stream>>>(aux, auxs, nullptr, node_grid);
    scan_add<<<node_grid, 256, 0, stream>>>(incl, auxs, NNODES);
    fill_csr<<<edge_grid, 256, 0, stream>>>(src, dst, incl, deg, cursor, csr_src);

    // ===== layer 1 =====
    gemm256<<<gemm_grid, 256, 0, stream>>>(x, W1, feat, NNODES);
    elr_kernel<<<elr_grid, 256, 0, stream>>>(feat, al1, ar1, el, er);
    gat_node<1><<<gat_grid, 256, 0, stream>>>(csr_src, incl, deg, el, er, feat, b1, h1);

    // ===== layer 2 =====
    gemm256<<<gemm_grid, 256, 0, stream>>>(h1, W2, feat, NNODES);
    elr_kernel<<<elr_grid, 256, 0, stream>>>(feat, al2, ar2, el, er);
    gat_node<2><<<gat_grid, 256, 0, stream>>>(csr_src, incl, deg, el, er, feat, b2, out);
}

// Round 3
// 458.518 us; speedup vs baseline: 13.6566x; 1.3050x over previous
//
#include <hip/hip_runtime.h>
#include <cstdint>
#include <cstddef>

#define NNODES 50000
#define NPAD   50048      // 782 * 64
#define NEDGES 800000
#define HEADS 4
#define HID 64
#define FDIM 256          // HEADS*HID == IN_DIM == 256
#define NEG_SLOPE 0.2f

typedef short bf16x8 __attribute__((ext_vector_type(8)));
typedef float f32x4  __attribute__((ext_vector_type(4)));

// ---------- helpers ----------
__device__ __forceinline__ float elu_f(float x) {
    return x > 0.0f ? x : expm1f(x);
}
__device__ __forceinline__ float lrelu_f(float x) {
    return x > 0.0f ? x : NEG_SLOPE * x;
}
__device__ __forceinline__ unsigned short f2bf_rn(float x) {
    unsigned u = __float_as_uint(x);
    unsigned r = u + 0x7FFFu + ((u >> 16) & 1u);
    return (unsigned short)(r >> 16);
}
__device__ __forceinline__ void split_bf16(float x, unsigned short& hi, unsigned short& lo) {
    hi = f2bf_rn(x);
    float fhi = __uint_as_float(((unsigned)hi) << 16);
    lo = f2bf_rn(x - fhi);
}

// ---------- input converts ----------
// x [50000][256] f32 -> hi/lo bf16 planes [NPAD][256] (pad rows zero)
__global__ __launch_bounds__(256) void xconv(const float* __restrict__ x,
                                             unsigned short* __restrict__ hi,
                                             unsigned short* __restrict__ lo) {
    int i = blockIdx.x * 256 + threadIdx.x;          // float4 chunk id
    if (i >= NPAD * 64) return;
    int row = i >> 6;
    float4 v = {0, 0, 0, 0};
    if (row < NNODES) v = ((const float4*)x)[i];
    ushort4 h4, l4;
    split_bf16(v.x, h4.x, l4.x);
    split_bf16(v.y, h4.y, l4.y);
    split_bf16(v.z, h4.z, l4.z);
    split_bf16(v.w, h4.w, l4.w);
    ((ushort4*)hi)[i] = h4;
    ((ushort4*)lo)[i] = l4;
}

// W [K=256][N=256] f32 -> WT hi/lo bf16 [N][K]
__global__ __launch_bounds__(256) void wconv(const float* __restrict__ W,
                                             unsigned short* __restrict__ wthi,
                                             unsigned short* __restrict__ wtlo) {
    int t = blockIdx.x * 256 + threadIdx.x;          // 0..65535
    int k = t >> 8, n = t & 255;
    unsigned short h, l;
    split_bf16(W[k * 256 + n], h, l);
    wthi[n * 256 + k] = h;
    wtlo[n * 256 + k] = l;
}

// ---------- split-bf16 MFMA GEMM + fused el/er ----------
// C[NPAD x 256] = A @ W  with A,W split into bf16 hi/lo.
// block: 256 thr (4 waves); tile 64 rows x 256 cols; K=256 staged once in LDS.
__global__ __launch_bounds__(256, 2) void gemm_mfma(const unsigned short* __restrict__ Ahi,
                                                    const unsigned short* __restrict__ Alo,
                                                    const unsigned short* __restrict__ WThi,
                                                    const unsigned short* __restrict__ WTlo,
                                                    const float* __restrict__ alv,
                                                    const float* __restrict__ arv,
                                                    float* __restrict__ feat,
                                                    float* __restrict__ el,
                                                    float* __restrict__ er) {
    __shared__ char smem[66560];                     // A: 2 planes x 32768B; C: 64x260 f32
    const int tid  = threadIdx.x;
    const int lane = tid & 63;
    const int wave = tid >> 6;
    const int block_row = blockIdx.x * 64;

    // ---- stage A tile (hi+lo, 64 rows x 256 k, XOR-swizzled) ----
    const unsigned short* aplane[2] = {Ahi + (size_t)block_row * 256,
                                       Alo + (size_t)block_row * 256};
    #pragma unroll
    for (int i = 0; i < 16; ++i) {
        int chunk = i * 256 + tid;                   // 16B chunks, 0..4095
        int p   = chunk >> 11;
        int row = (chunk >> 5) & 63;
        int c   = chunk & 31;
        uint4 v = *(const uint4*)(aplane[p] + row * 256 + c * 8);
        int off = p * 32768 + row * 512 + ((c * 16) ^ ((row & 7) << 4));
        *(uint4*)(smem + off) = v;
    }
    __syncthreads();

    // ---- K-loop: 8 steps of 32, 48 MFMA per step ----
    f32x4 acc[4][4];
    #pragma unroll
    for (int m = 0; m < 4; ++m)
        #pragma unroll
        for (int n = 0; n < 4; ++n)
            acc[m][n] = (f32x4){0, 0, 0, 0};

    const int g = lane >> 4;                         // 0..3
    int arow[4], aswz[4];
    #pragma unroll
    for (int m = 0; m < 4; ++m) {
        int row = m * 16 + (lane & 15);
        arow[m] = row * 512;
        aswz[m] = (row & 7) << 4;
    }
    const unsigned short* wb[2][4];
    #pragma unroll
    for (int n = 0; n < 4; ++n) {
        int col = wave * 64 + n * 16 + (lane & 15);
        wb[0][n] = WThi + col * 256 + g * 8;
        wb[1][n] = WTlo + col * 256 + g * 8;
    }

    #pragma unroll
    for (int t = 0; t < 8; ++t) {
        bf16x8 ah[4], al_[4], wh[4], wl[4];
        int koff = t * 64 + g * 16;                  // byte offset of 16B chunk in row
        #pragma unroll
        for (int m = 0; m < 4; ++m) {
            ah[m]  = *(const bf16x8*)(smem + arow[m] + (koff ^ aswz[m]));
            al_[m] = *(const bf16x8*)(smem + 32768 + arow[m] + (koff ^ aswz[m]));
        }
        #pragma unroll
        for (int n = 0; n < 4; ++n) {
            wh[n] = *(const bf16x8*)(wb[0][n] + t * 32);
            wl[n] = *(const bf16x8*)(wb[1][n] + t * 32);
        }
        #pragma unroll
        for (int m = 0; m < 4; ++m)
            #pragma unroll
            for (int n = 0; n < 4; ++n) {
                acc[m][n] = __builtin_amdgcn_mfma_f32_16x16x32_bf16(ah[m],  wh[n], acc[m][n], 0, 0, 0);
                acc[m][n] = __builtin_amdgcn_mfma_f32_16x16x32_bf16(ah[m],  wl[n], acc[m][n], 0, 0, 0);
                acc[m][n] = __builtin_amdgcn_mfma_f32_16x16x32_bf16(al_[m], wh[n], acc[m][n], 0, 0, 0);
            }
    }

    // ---- epilogue: C -> LDS (row-major [64][260]) ----
    __syncthreads();                                 // A planes dead
    float* C = (float*)smem;
    #pragma unroll
    for (int m = 0; m < 4; ++m) {
        int r0 = m * 16 + g * 4;
        #pragma unroll
        for (int n = 0; n < 4; ++n) {
            int col = wave * 64 + n * 16 + (lane & 15);
            C[(r0 + 0) * 260 + col] = acc[m][n][0];
            C[(r0 + 1) * 260 + col] = acc[m][n][1];
            C[(r0 + 2) * 260 + col] = acc[m][n][2];
            C[(r0 + 3) * 260 + col] = acc[m][n][3];
        }
    }
    __syncthreads();

    // coalesced feat write
    #pragma unroll
    for (int i = 0; i < 16; ++i) {
        int flat = i * 256 + tid;                    // 0..4095
        int r  = flat >> 6;
        int c4 = flat & 63;
        float4 v = *(float4*)(C + r * 260 + c4 * 4);
        *(float4*)(feat + (size_t)(block_row + r) * FDIM + c4 * 4) = v;
    }

    // fused el/er: thread t -> (head = t>>6, node = t&63)
    int h = wave, node = lane;
    float sl = 0.0f, sr = 0.0f;
    #pragma unroll 8
    for (int d = 0; d < 64; ++d) {
        float v = C[node * 260 + h * 64 + d];
        sl += v * alv[h * 64 + d];
        sr += v * arv[h * 64 + d];
    }
    el[(block_row + node) * HEADS + h] = sl;
    er[(block_row + node) * HEADS + h] = sr;
}

// ---------- CSR build ----------
__global__ __launch_bounds__(256) void count_deg(const int* __restrict__ dst,
                                                 int* __restrict__ deg) {
    int e = blockIdx.x * 256 + threadIdx.x;
    if (e < NEDGES) atomicAdd(&deg[dst[e]], 1);
}

__global__ __launch_bounds__(256) void scan_block(const int* __restrict__ in,
                                                  int* __restrict__ out,
                                                  int* __restrict__ bsums, int n) {
    int gid = blockIdx.x * 256 + threadIdx.x;
    int v = (gid < n) ? in[gid] : 0;
    int lane = threadIdx.x & 63;
    #pragma unroll
    for (int off = 1; off < 64; off <<= 1) {
        int t = __shfl_up(v, off, 64);
        if (lane >= off) v += t;
    }
    __shared__ int wsum[4];
    int wid = threadIdx.x >> 6;
    if (lane == 63) wsum[wid] = v;
    __syncthreads();
    int add = 0;
    for (int w = 0; w < wid; ++w) add += wsum[w];
    v += add;
    if (gid < n) out[gid] = v;
    if (bsums && threadIdx.x == 255) bsums[blockIdx.x] = v;
}

__global__ __launch_bounds__(256) void scan_add(int* __restrict__ out,
                                                const int* __restrict__ bscan, int n) {
    int gid = blockIdx.x * 256 + threadIdx.x;
    if (blockIdx.x > 0 && gid < n) out[gid] += bscan[blockIdx.x - 1];
}

__global__ __launch_bounds__(256) void fill_csr(const int* __restrict__ src,
                                                const int* __restrict__ dst,
                                                const int* __restrict__ incl,
                                                const int* __restrict__ deg,
                                                int* __restrict__ cursor,
                                                int* __restrict__ csr_src) {
    int e = blockIdx.x * 256 + threadIdx.x;
    if (e >= NEDGES) return;
    int s = src[e], d = dst[e];
    int start = incl[d] - deg[d];
    int pos = start + atomicAdd(&cursor[d], 1);
    csr_src[pos] = s;
}

// ---------- fused per-node softmax + aggregate + bias + ELU ----------
// one 64-lane wave per dst node; 4 waves per block.
// LAYER==1: write bf16 hi/lo planes [NPAD][256]; LAYER==2: f32 out [head][node][64]
template <int LAYER>
__global__ __launch_bounds__(256) void gat_node(const int* __restrict__ csr_src,
                                                const int* __restrict__ incl,
                                                const int* __restrict__ deg,
                                                const float* __restrict__ el,
                                                const float* __restrict__ er,
                                                const float* __restrict__ feat,
                                                const float* __restrict__ bias,
                                                float* __restrict__ outp,
                                                unsigned short* __restrict__ ohi,
                                                unsigned short* __restrict__ olo) {
    int node = blockIdx.x * 4 + (threadIdx.x >> 6);
    if (node >= NNODES) return;
    int lane = threadIdx.x & 63;
    int h = lane >> 4;

    int end = incl[node];
    int dg = deg[node];
    int start = end - dg;

    float4 r4 = ((const float4*)er)[node];

    // pass A: per-head max
    float m0 = -INFINITY, m1 = -INFINITY, m2 = -INFINITY, m3 = -INFINITY;
    for (int i = start + lane; i < end; i += 64) {
        int s = csr_src[i];
        float4 l4 = ((const float4*)el)[s];
        m0 = fmaxf(m0, lrelu_f(l4.x + r4.x));
        m1 = fmaxf(m1, lrelu_f(l4.y + r4.y));
        m2 = fmaxf(m2, lrelu_f(l4.z + r4.z));
        m3 = fmaxf(m3, lrelu_f(l4.w + r4.w));
    }
    #pragma unroll
    for (int off = 1; off < 64; off <<= 1) {
        m0 = fmaxf(m0, __shfl_xor(m0, off, 64));
        m1 = fmaxf(m1, __shfl_xor(m1, off, 64));
        m2 = fmaxf(m2, __shfl_xor(m2, off, 64));
        m3 = fmaxf(m3, __shfl_xor(m3, off, 64));
    }

    // pass B: denom
    float s0 = 0, s1 = 0, s2 = 0, s3 = 0;
    for (int i = start + lane; i < end; i += 64) {
        int s = csr_src[i];
        float4 l4 = ((const float4*)el)[s];
        s0 += expf(lrelu_f(l4.x + r4.x) - m0);
        s1 += expf(lrelu_f(l4.y + r4.y) - m1);
        s2 += expf(lrelu_f(l4.z + r4.z) - m2);
        s3 += expf(lrelu_f(l4.w + r4.w) - m3);
    }
    #pragma unroll
    for (int off = 1; off < 64; off <<= 1) {
        s0 += __shfl_xor(s0, off, 64);
        s1 += __shfl_xor(s1, off, 64);
        s2 += __shfl_xor(s2, off, 64);
        s3 += __shfl_xor(s3, off, 64);
    }

    float m_h     = (h == 0) ? m0 : (h == 1) ? m1 : (h == 2) ? m2 : m3;
    float den_h   = (h == 0) ? s0 : (h == 1) ? s1 : (h == 2) ? s2 : s3;
    float er_h    = (h == 0) ? r4.x : (h == 1) ? r4.y : (h == 2) ? r4.z : r4.w;
    float inv_den = 1.0f / den_h;

    // pass C: gather-aggregate
    float4 acc = {0, 0, 0, 0};
    for (int base = start; base < end; base += 64) {
        int cnt = min(64, end - base);
        int sp = (base + lane < end) ? csr_src[base + lane] : 0;
        for (int j = 0; j < cnt; ++j) {
            int s = __shfl(sp, j, 64);
            float sc = lrelu_f(el[s * HEADS + h] + er_h);
            float alpha = expf(sc - m_h) * inv_den;
            float4 f = *(const float4*)(feat + (size_t)s * FDIM + lane * 4);
            acc.x += f.x * alpha;
            acc.y += f.y * alpha;
            acc.z += f.z * alpha;
            acc.w += f.w * alpha;
        }
    }

    float4 b = ((const float4*)bias)[lane];
    acc.x = elu_f(acc.x + b.x);
    acc.y = elu_f(acc.y + b.y);
    acc.z = elu_f(acc.z + b.z);
    acc.w = elu_f(acc.w + b.w);

    if (LAYER == 1) {
        ushort4 h4, l4;
        split_bf16(acc.x, h4.x, l4.x);
        split_bf16(acc.y, h4.y, l4.y);
        split_bf16(acc.z, h4.z, l4.z);
        split_bf16(acc.w, h4.w, l4.w);
        *(ushort4*)(ohi + (size_t)node * FDIM + lane * 4) = h4;
        *(ushort4*)(olo + (size_t)node * FDIM + lane * 4) = l4;
    } else {
        *(float4*)(outp + ((size_t)h * NNODES + node) * HID + (lane & 15) * 4) = acc;
    }
}

// ---------- launch ----------
extern "C" void kernel_launch(void* const* d_in, const int* in_sizes, int n_in,
                              void* d_out, int out_size, void* d_ws, size_t ws_size,
                              hipStream_t stream) {
    const float* x   = (const float*)d_in[0];
    const int*   src = (const int*)d_in[1];
    const int*   dst = (const int*)d_in[2];
    const float* W1  = (const float*)d_in[3];
    const float* al1 = (const float*)d_in[4];
    const float* ar1 = (const float*)d_in[5];
    const float* b1  = (const float*)d_in[6];
    const float* W2  = (const float*)d_in[7];
    const float* al2 = (const float*)d_in[8];
    const float* ar2 = (const float*)d_in[9];
    const float* b2  = (const float*)d_in[10];
    float* out = (float*)d_out;

    float* ws = (float*)d_ws;
    float*          feat = ws;                                       // NPAD*256 f32
    unsigned short* abhi = (unsigned short*)(feat + (size_t)NPAD * FDIM);  // NPAD*256 u16
    unsigned short* ablo = abhi + (size_t)NPAD * FDIM;
    unsigned short* wt1h = ablo + (size_t)NPAD * FDIM;               // 65536 u16 each
    unsigned short* wt1l = wt1h + 65536;
    unsigned short* wt2h = wt1l + 65536;
    unsigned short* wt2l = wt2h + 65536;
    float* el = (float*)(wt2l + 65536);                              // NPAD*4
    float* er = el + (size_t)NPAD * HEADS;
    int* deg     = (int*)(er + (size_t)NPAD * HEADS);
    int* incl    = deg + NNODES;
    int* cursor  = incl + NNODES;
    int* aux     = cursor + NNODES;
    int* auxs    = aux + 256;
    int* csr_src = auxs + 256;

    const int edge_grid = (NEDGES + 255) / 256;       // 3125
    const int node_grid = (NNODES + 255) / 256;       // 196
    const int gat_grid  = (NNODES + 3) / 4;           // 12500
    const int gemm_grid = NPAD / 64;                  // 782
    const int xconv_grid = (NPAD * 64) / 256;         // 12512

    // ===== converts =====
    wconv<<<256, 256, 0, stream>>>(W1, wt1h, wt1l);
    wconv<<<256, 256, 0, stream>>>(W2, wt2h, wt2l);
    xconv<<<xconv_grid, 256, 0, stream>>>(x, abhi, ablo);

    // ===== CSR build =====
    hipMemsetAsync(deg,    0, NNODES * sizeof(int), stream);
    hipMemsetAsync(cursor, 0, NNODES * sizeof(int), stream);
    count_deg<<<edge_grid, 256, 0, stream>>>(dst, deg);
    scan_block<<<node_grid, 256, 0, stream>>>(deg, incl, aux, NNODES);
    scan_block<<<1, 256, 0, stream>>>(aux, auxs, nullptr, node_grid);
    scan_add<<<node_grid, 256, 0, stream>>>(incl, auxs, NNODES);
    fill_csr<<<edge_grid, 256, 0, stream>>>(src, dst, incl, deg, cursor, csr_src);

    // ===== layer 1 =====
    gemm_mfma<<<gemm_grid, 256, 0, stream>>>(abhi, ablo, wt1h, wt1l, al1, ar1, feat, el, er);
    gat_node<1><<<gat_grid, 256, 0, stream>>>(csr_src, incl, deg, el, er, feat, b1,
                                              nullptr, abhi, ablo);

    // ===== layer 2 =====
    gemm_mfma<<<gemm_grid, 256, 0, stream>>>(abhi, ablo, wt2h, wt2l, al2, ar2, feat, el, er);
    gat_node<2><<<gat_grid, 256, 0, stream>>>(csr_src, incl, deg, el, er, feat, b2,
                                              out, nullptr, nullptr);
}

// Round 4
// 371.631 us; speedup vs baseline: 16.8495x; 1.2338x over previous
//
#include <hip/hip_runtime.h>
#include <cstdint>
#include <cstddef>

#define NNODES 50000
#define NPAD   50048      // 782 * 64
#define NEDGES 800000
#define HEADS 4
#define HID 64
#define FDIM 256          // HEADS*HID == IN_DIM == 256
#define NEG_SLOPE 0.2f

typedef short bf16x8 __attribute__((ext_vector_type(8)));
typedef float f32x4  __attribute__((ext_vector_type(4)));

// ---------- helpers ----------
__device__ __forceinline__ float elu_f(float x) {
    return x > 0.0f ? x : expm1f(x);
}
__device__ __forceinline__ float lrelu_f(float x) {
    return x > 0.0f ? x : NEG_SLOPE * x;
}
__device__ __forceinline__ unsigned short f2bf_rn(float x) {
    unsigned u = __float_as_uint(x);
    unsigned r = u + 0x7FFFu + ((u >> 16) & 1u);
    return (unsigned short)(r >> 16);
}
__device__ __forceinline__ void split_bf16(float x, unsigned short& hi, unsigned short& lo) {
    hi = f2bf_rn(x);
    float fhi = __uint_as_float(((unsigned)hi) << 16);
    lo = f2bf_rn(x - fhi);
}
__device__ __forceinline__ float bf2f(unsigned short u) {
    return __uint_as_float(((unsigned)u) << 16);
}

// ---------- input converts ----------
__global__ __launch_bounds__(256) void xconv(const float* __restrict__ x,
                                             unsigned short* __restrict__ hi,
                                             unsigned short* __restrict__ lo) {
    int i = blockIdx.x * 256 + threadIdx.x;          // float4 chunk id
    if (i >= NPAD * 64) return;
    int row = i >> 6;
    float4 v = {0, 0, 0, 0};
    if (row < NNODES) v = ((const float4*)x)[i];
    ushort4 h4, l4;
    split_bf16(v.x, h4.x, l4.x);
    split_bf16(v.y, h4.y, l4.y);
    split_bf16(v.z, h4.z, l4.z);
    split_bf16(v.w, h4.w, l4.w);
    ((ushort4*)hi)[i] = h4;
    ((ushort4*)lo)[i] = l4;
}

// W [K=256][N=256] f32 -> WT hi/lo bf16 [N][K]
__global__ __launch_bounds__(256) void wconv(const float* __restrict__ W,
                                             unsigned short* __restrict__ wthi,
                                             unsigned short* __restrict__ wtlo) {
    int t = blockIdx.x * 256 + threadIdx.x;          // 0..65535
    int k = t >> 8, n = t & 255;
    unsigned short h, l;
    split_bf16(W[k * 256 + n], h, l);
    wthi[n * 256 + k] = h;
    wtlo[n * 256 + k] = l;
}

// ---------- split-bf16 MFMA GEMM + fused el/er; output = bf16-hi plane ----------
#define CSTR 261
__global__ __launch_bounds__(256, 2) void gemm_mfma(const unsigned short* __restrict__ Ahi,
                                                    const unsigned short* __restrict__ Alo,
                                                    const unsigned short* __restrict__ WThi,
                                                    const unsigned short* __restrict__ WTlo,
                                                    const float* __restrict__ alv,
                                                    const float* __restrict__ arv,
                                                    unsigned short* __restrict__ fbh,
                                                    float* __restrict__ el,
                                                    float* __restrict__ er) {
    __shared__ char smem[66816];                     // A: 2x32768B; C: 64x261 f32
    const int tid  = threadIdx.x;
    const int lane = tid & 63;
    const int wave = tid >> 6;
    const int block_row = blockIdx.x * 64;

    // ---- stage A tile (hi+lo, 64 rows x 256 k, XOR-swizzled) ----
    const unsigned short* aplane[2] = {Ahi + (size_t)block_row * 256,
                                       Alo + (size_t)block_row * 256};
    #pragma unroll
    for (int i = 0; i < 16; ++i) {
        int chunk = i * 256 + tid;                   // 16B chunks, 0..4095
        int p   = chunk >> 11;
        int row = (chunk >> 5) & 63;
        int c   = chunk & 31;
        uint4 v = *(const uint4*)(aplane[p] + row * 256 + c * 8);
        int off = p * 32768 + row * 512 + ((c * 16) ^ ((row & 7) << 4));
        *(uint4*)(smem + off) = v;
    }
    __syncthreads();

    // ---- K-loop ----
    f32x4 acc[4][4];
    #pragma unroll
    for (int m = 0; m < 4; ++m)
        #pragma unroll
        for (int n = 0; n < 4; ++n)
            acc[m][n] = (f32x4){0, 0, 0, 0};

    const int g = lane >> 4;                         // 0..3
    int arow[4], aswz[4];
    #pragma unroll
    for (int m = 0; m < 4; ++m) {
        int row = m * 16 + (lane & 15);
        arow[m] = row * 512;
        aswz[m] = (row & 7) << 4;
    }
    const unsigned short* wb[2][4];
    #pragma unroll
    for (int n = 0; n < 4; ++n) {
        int col = wave * 64 + n * 16 + (lane & 15);
        wb[0][n] = WThi + col * 256 + g * 8;
        wb[1][n] = WTlo + col * 256 + g * 8;
    }

    #pragma unroll
    for (int t = 0; t < 8; ++t) {
        bf16x8 ah[4], al_[4], wh[4], wl[4];
        int koff = t * 64 + g * 16;
        #pragma unroll
        for (int m = 0; m < 4; ++m) {
            ah[m]  = *(const bf16x8*)(smem + arow[m] + (koff ^ aswz[m]));
            al_[m] = *(const bf16x8*)(smem + 32768 + arow[m] + (koff ^ aswz[m]));
        }
        #pragma unroll
        for (int n = 0; n < 4; ++n) {
            wh[n] = *(const bf16x8*)(wb[0][n] + t * 32);
            wl[n] = *(const bf16x8*)(wb[1][n] + t * 32);
        }
        #pragma unroll
        for (int m = 0; m < 4; ++m)
            #pragma unroll
            for (int n = 0; n < 4; ++n) {
                acc[m][n] = __builtin_amdgcn_mfma_f32_16x16x32_bf16(ah[m],  wh[n], acc[m][n], 0, 0, 0);
                acc[m][n] = __builtin_amdgcn_mfma_f32_16x16x32_bf16(ah[m],  wl[n], acc[m][n], 0, 0, 0);
                acc[m][n] = __builtin_amdgcn_mfma_f32_16x16x32_bf16(al_[m], wh[n], acc[m][n], 0, 0, 0);
            }
    }

    // ---- epilogue: C -> LDS (row-major [64][261]) ----
    __syncthreads();                                 // A planes dead
    float* C = (float*)smem;
    #pragma unroll
    for (int m = 0; m < 4; ++m) {
        int r0 = m * 16 + g * 4;
        #pragma unroll
        for (int n = 0; n < 4; ++n) {
            int col = wave * 64 + n * 16 + (lane & 15);
            C[(r0 + 0) * CSTR + col] = acc[m][n][0];
            C[(r0 + 1) * CSTR + col] = acc[m][n][1];
            C[(r0 + 2) * CSTR + col] = acc[m][n][2];
            C[(r0 + 3) * CSTR + col] = acc[m][n][3];
        }
    }
    __syncthreads();

    // coalesced bf16-hi feat write: 64 rows x 32 chunks of 16B
    #pragma unroll
    for (int i = 0; i < 8; ++i) {
        int flat = i * 256 + tid;                    // 0..2047
        int r  = flat >> 5;
        int c8 = flat & 31;
        const float* cp = C + r * CSTR + c8 * 8;
        unsigned short us[8];
        #pragma unroll
        for (int k = 0; k < 8; ++k) us[k] = f2bf_rn(cp[k]);
        uint4 pk;
        pk.x = (unsigned)us[0] | ((unsigned)us[1] << 16);
        pk.y = (unsigned)us[2] | ((unsigned)us[3] << 16);
        pk.z = (unsigned)us[4] | ((unsigned)us[5] << 16);
        pk.w = (unsigned)us[6] | ((unsigned)us[7] << 16);
        *(uint4*)(fbh + (size_t)(block_row + r) * FDIM + c8 * 8) = pk;
    }

    // fused el/er: thread t -> (head = wave, node = lane)
    int h = wave, node = lane;
    float sl = 0.0f, sr = 0.0f;
    #pragma unroll 8
    for (int d = 0; d < 64; ++d) {
        float v = C[node * CSTR + h * 64 + d];
        sl += v * alv[h * 64 + d];
        sr += v * arv[h * 64 + d];
    }
    el[(block_row + node) * HEADS + h] = sl;
    er[(block_row + node) * HEADS + h] = sr;
}

// ---------- CSR build ----------
__global__ __launch_bounds__(256) void count_deg(const int* __restrict__ dst,
                                                 int* __restrict__ deg) {
    int e = blockIdx.x * 256 + threadIdx.x;
    if (e < NEDGES) atomicAdd(&deg[dst[e]], 1);
}

__global__ __launch_bounds__(256) void scan_block(const int* __restrict__ in,
                                                  int* __restrict__ out,
                                                  int* __restrict__ bsums, int n) {
    int gid = blockIdx.x * 256 + threadIdx.x;
    int v = (gid < n) ? in[gid] : 0;
    int lane = threadIdx.x & 63;
    #pragma unroll
    for (int off = 1; off < 64; off <<= 1) {
        int t = __shfl_up(v, off, 64);
        if (lane >= off) v += t;
    }
    __shared__ int wsum[4];
    int wid = threadIdx.x >> 6;
    if (lane == 63) wsum[wid] = v;
    __syncthreads();
    int add = 0;
    for (int w = 0; w < wid; ++w) add += wsum[w];
    v += add;
    if (gid < n) out[gid] = v;
    if (bsums && threadIdx.x == 255) bsums[blockIdx.x] = v;
}

__global__ __launch_bounds__(256) void scan_add(int* __restrict__ out,
                                                const int* __restrict__ bscan, int n) {
    int gid = blockIdx.x * 256 + threadIdx.x;
    if (blockIdx.x > 0 && gid < n) out[gid] += bscan[blockIdx.x - 1];
}

__global__ __launch_bounds__(256) void fill_csr(const int* __restrict__ src,
                                                const int* __restrict__ dst,
                                                const int* __restrict__ incl,
                                                const int* __restrict__ deg,
                                                int* __restrict__ cursor,
                                                int* __restrict__ csr_src) {
    int e = blockIdx.x * 256 + threadIdx.x;
    if (e >= NEDGES) return;
    int s = src[e], d = dst[e];
    int start = incl[d] - deg[d];
    int pos = start + atomicAdd(&cursor[d], 1);
    csr_src[pos] = s;
}

// ---------- fused per-node softmax + aggregate + bias + ELU ----------
// one 64-lane wave per dst node; 4 waves per block; alpha staged in LDS.
// LAYER==1: write bf16 hi/lo planes; LAYER==2: f32 out [head][node][64]
template <int LAYER>
__global__ __launch_bounds__(256) void gat_node(const int* __restrict__ csr_src,
                                                const int* __restrict__ incl,
                                                const int* __restrict__ deg,
                                                const float* __restrict__ el,
                                                const float* __restrict__ er,
                                                const unsigned short* __restrict__ fbh,
                                                const float* __restrict__ bias,
                                                float* __restrict__ outp,
                                                unsigned short* __restrict__ ohi,
                                                unsigned short* __restrict__ olo) {
    __shared__ float alds[4][64][4];
    __shared__ int   slds[4][64];
    int wv   = threadIdx.x >> 6;
    int node = blockIdx.x * 4 + wv;
    if (node >= NNODES) return;
    int lane = threadIdx.x & 63;
    int h = lane >> 4;

    int end   = incl[node];
    int dg    = deg[node];
    int start = end - dg;
    float4 r4 = ((const float4*)er)[node];
    float4 acc = {0, 0, 0, 0};

    if (dg <= 64) {
        // ---- fast path: all scores in registers, single pass ----
        bool act = lane < dg;
        int s = act ? csr_src[start + lane] : 0;
        float4 l4 = ((const float4*)el)[s];
        float c0 = act ? lrelu_f(l4.x + r4.x) : -INFINITY;
        float c1 = act ? lrelu_f(l4.y + r4.y) : -INFINITY;
        float c2 = act ? lrelu_f(l4.z + r4.z) : -INFINITY;
        float c3 = act ? lrelu_f(l4.w + r4.w) : -INFINITY;
        float m0 = c0, m1 = c1, m2 = c2, m3 = c3;
        #pragma unroll
        for (int off = 1; off < 64; off <<= 1) {
            m0 = fmaxf(m0, __shfl_xor(m0, off, 64));
            m1 = fmaxf(m1, __shfl_xor(m1, off, 64));
            m2 = fmaxf(m2, __shfl_xor(m2, off, 64));
            m3 = fmaxf(m3, __shfl_xor(m3, off, 64));
        }
        float p0 = act ? expf(c0 - m0) : 0.0f;
        float p1 = act ? expf(c1 - m1) : 0.0f;
        float p2 = act ? expf(c2 - m2) : 0.0f;
        float p3 = act ? expf(c3 - m3) : 0.0f;
        float s0 = p0, s1 = p1, s2 = p2, s3 = p3;
        #pragma unroll
        for (int off = 1; off < 64; off <<= 1) {
            s0 += __shfl_xor(s0, off, 64);
            s1 += __shfl_xor(s1, off, 64);
            s2 += __shfl_xor(s2, off, 64);
            s3 += __shfl_xor(s3, off, 64);
        }
        float4 a4 = {p0 / s0, p1 / s1, p2 / s2, p3 / s3};
        *(float4*)(&alds[wv][lane][0]) = a4;
        slds[wv][lane] = s;
        __builtin_amdgcn_wave_barrier();

        #pragma unroll 4
        for (int j = 0; j < dg; ++j) {
            float a = alds[wv][j][h];
            int   sj = slds[wv][j];
            ushort4 f = *(const ushort4*)(fbh + (size_t)sj * FDIM + lane * 4);
            acc.x += bf2f(f.x) * a;
            acc.y += bf2f(f.y) * a;
            acc.z += bf2f(f.z) * a;
            acc.w += bf2f(f.w) * a;
        }
    } else {
        // ---- slow path (deg > 64): two-pass max/denom, chunked gather ----
        float m0 = -INFINITY, m1 = -INFINITY, m2 = -INFINITY, m3 = -INFINITY;
        for (int i = start + lane; i < end; i += 64) {
            int s = csr_src[i];
            float4 l4 = ((const float4*)el)[s];
            m0 = fmaxf(m0, lrelu_f(l4.x + r4.x));
            m1 = fmaxf(m1, lrelu_f(l4.y + r4.y));
            m2 = fmaxf(m2, lrelu_f(l4.z + r4.z));
            m3 = fmaxf(m3, lrelu_f(l4.w + r4.w));
        }
        #pragma unroll
        for (int off = 1; off < 64; off <<= 1) {
            m0 = fmaxf(m0, __shfl_xor(m0, off, 64));
            m1 = fmaxf(m1, __shfl_xor(m1, off, 64));
            m2 = fmaxf(m2, __shfl_xor(m2, off, 64));
            m3 = fmaxf(m3, __shfl_xor(m3, off, 64));
        }
        float s0 = 0, s1 = 0, s2 = 0, s3 = 0;
        for (int i = start + lane; i < end; i += 64) {
            int s = csr_src[i];
            float4 l4 = ((const float4*)el)[s];
            s0 += expf(lrelu_f(l4.x + r4.x) - m0);
            s1 += expf(lrelu_f(l4.y + r4.y) - m1);
            s2 += expf(lrelu_f(l4.z + r4.z) - m2);
            s3 += expf(lrelu_f(l4.w + r4.w) - m3);
        }
        #pragma unroll
        for (int off = 1; off < 64; off <<= 1) {
            s0 += __shfl_xor(s0, off, 64);
            s1 += __shfl_xor(s1, off, 64);
            s2 += __shfl_xor(s2, off, 64);
            s3 += __shfl_xor(s3, off, 64);
        }
        float i0 = 1.0f / s0, i1 = 1.0f / s1, i2 = 1.0f / s2, i3 = 1.0f / s3;

        for (int base = start; base < end; base += 64) {
            int cnt = min(64, end - base);
            if (lane < cnt) {
                int s = csr_src[base + lane];
                float4 l4 = ((const float4*)el)[s];
                float4 a4;
                a4.x = expf(lrelu_f(l4.x + r4.x) - m0) * i0;
                a4.y = expf(lrelu_f(l4.y + r4.y) - m1) * i1;
                a4.z = expf(lrelu_f(l4.z + r4.z) - m2) * i2;
                a4.w = expf(lrelu_f(l4.w + r4.w) - m3) * i3;
                *(float4*)(&alds[wv][lane][0]) = a4;
                slds[wv][lane] = s;
            }
            __builtin_amdgcn_wave_barrier();
            for (int j = 0; j < cnt; ++j) {
                float a = alds[wv][j][h];
                int   sj = slds[wv][j];
                ushort4 f = *(const ushort4*)(fbh + (size_t)sj * FDIM + lane * 4);
                acc.x += bf2f(f.x) * a;
                acc.y += bf2f(f.y) * a;
                acc.z += bf2f(f.z) * a;
                acc.w += bf2f(f.w) * a;
            }
            __builtin_amdgcn_wave_barrier();
        }
    }

    float4 b = ((const float4*)bias)[lane];
    acc.x = elu_f(acc.x + b.x);
    acc.y = elu_f(acc.y + b.y);
    acc.z = elu_f(acc.z + b.z);
    acc.w = elu_f(acc.w + b.w);

    if (LAYER == 1) {
        ushort4 h4, l4;
        split_bf16(acc.x, h4.x, l4.x);
        split_bf16(acc.y, h4.y, l4.y);
        split_bf16(acc.z, h4.z, l4.z);
        split_bf16(acc.w, h4.w, l4.w);
        *(ushort4*)(ohi + (size_t)node * FDIM + lane * 4) = h4;
        *(ushort4*)(olo + (size_t)node * FDIM + lane * 4) = l4;
    } else {
        *(float4*)(outp + ((size_t)h * NNODES + node) * HID + (lane & 15) * 4) = acc;
    }
}

// ---------- launch ----------
extern "C" void kernel_launch(void* const* d_in, const int* in_sizes, int n_in,
                              void* d_out, int out_size, void* d_ws, size_t ws_size,
                              hipStream_t stream) {
    const float* x   = (const float*)d_in[0];
    const int*   src = (const int*)d_in[1];
    const int*   dst = (const int*)d_in[2];
    const float* W1  = (const float*)d_in[3];
    const float* al1 = (const float*)d_in[4];
    const float* ar1 = (const float*)d_in[5];
    const float* b1  = (const float*)d_in[6];
    const float* W2  = (const float*)d_in[7];
    const float* al2 = (const float*)d_in[8];
    const float* ar2 = (const float*)d_in[9];
    const float* b2  = (const float*)d_in[10];
    float* out = (float*)d_out;

    unsigned short* fbh  = (unsigned short*)d_ws;                    // NPAD*256 u16
    unsigned short* abhi = fbh  + (size_t)NPAD * FDIM;
    unsigned short* ablo = abhi + (size_t)NPAD * FDIM;
    unsigned short* wt1h = ablo + (size_t)NPAD * FDIM;               // 65536 each
    unsigned short* wt1l = wt1h + 65536;
    unsigned short* wt2h = wt1l + 65536;
    unsigned short* wt2l = wt2h + 65536;
    float* el = (float*)(wt2l + 65536);                              // NPAD*4
    float* er = el + (size_t)NPAD * HEADS;
    int* deg     = (int*)(er + (size_t)NPAD * HEADS);
    int* incl    = deg + NNODES;
    int* cursor  = incl + NNODES;
    int* aux     = cursor + NNODES;
    int* auxs    = aux + 256;
    int* csr_src = auxs + 256;

    const int edge_grid  = (NEDGES + 255) / 256;       // 3125
    const int node_grid  = (NNODES + 255) / 256;       // 196
    const int gat_grid   = (NNODES + 3) / 4;           // 12500
    const int gemm_grid  = NPAD / 64;                  // 782
    const int xconv_grid = (NPAD * 64) / 256;          // 12512

    // ===== converts =====
    wconv<<<256, 256, 0, stream>>>(W1, wt1h, wt1l);
    wconv<<<256, 256, 0, stream>>>(W2, wt2h, wt2l);
    xconv<<<xconv_grid, 256, 0, stream>>>(x, abhi, ablo);

    // ===== CSR build =====
    hipMemsetAsync(deg,    0, NNODES * sizeof(int), stream);
    hipMemsetAsync(cursor, 0, NNODES * sizeof(int), stream);
    count_deg<<<edge_grid, 256, 0, stream>>>(dst, deg);
    scan_block<<<node_grid, 256, 0, stream>>>(deg, incl, aux, NNODES);
    scan_block<<<1, 256, 0, stream>>>(aux, auxs, nullptr, node_grid);
    scan_add<<<node_grid, 256, 0, stream>>>(incl, auxs, NNODES);
    fill_csr<<<edge_grid, 256, 0, stream>>>(src, dst, incl, deg, cursor, csr_src);

    // ===== layer 1 =====
    gemm_mfma<<<gemm_grid, 256, 0, stream>>>(abhi, ablo, wt1h, wt1l, al1, ar1, fbh, el, er);
    gat_node<1><<<gat_grid, 256, 0, stream>>>(csr_src, incl, deg, el, er, fbh, b1,
                                              nullptr, abhi, ablo);

    // ===== layer 2 =====
    gemm_mfma<<<gemm_grid, 256, 0, stream>>>(abhi, ablo, wt2h, wt2l, al2, ar2, fbh, el, er);
    gat_node<2><<<gat_grid, 256, 0, stream>>>(csr_src, incl, deg, el, er, fbh, b2,
                                              out, nullptr, nullptr);
}

// Round 5
// 369.155 us; speedup vs baseline: 16.9625x; 1.0067x over previous
//
#include <hip/hip_runtime.h>
#include <cstdint>
#include <cstddef>

#define NNODES 50000
#define NPAD   50048      // 782 * 64
#define NEDGES 800000
#define HEADS 4
#define HID 64
#define FDIM 256          // HEADS*HID == IN_DIM == 256
#define NEG_SLOPE 0.2f

typedef short bf16x8 __attribute__((ext_vector_type(8)));
typedef float f32x4  __attribute__((ext_vector_type(4)));

// ---------- helpers ----------
__device__ __forceinline__ float elu_f(float x) {
    return x > 0.0f ? x : expm1f(x);
}
__device__ __forceinline__ float lrelu_f(float x) {
    return x > 0.0f ? x : NEG_SLOPE * x;
}
__device__ __forceinline__ unsigned short f2bf_rn(float x) {
    unsigned u = __float_as_uint(x);
    unsigned r = u + 0x7FFFu + ((u >> 16) & 1u);
    return (unsigned short)(r >> 16);
}
__device__ __forceinline__ void split_bf16(float x, unsigned short& hi, unsigned short& lo) {
    hi = f2bf_rn(x);
    float fhi = __uint_as_float(((unsigned)hi) << 16);
    lo = f2bf_rn(x - fhi);
}
__device__ __forceinline__ float bf2f(unsigned short u) {
    return __uint_as_float(((unsigned)u) << 16);
}

// ---------- input converts ----------
__global__ __launch_bounds__(256) void xconv(const float* __restrict__ x,
                                             unsigned short* __restrict__ hi,
                                             unsigned short* __restrict__ lo) {
    int i = blockIdx.x * 256 + threadIdx.x;          // float4 chunk id
    if (i >= NPAD * 64) return;
    int row = i >> 6;
    float4 v = {0, 0, 0, 0};
    if (row < NNODES) v = ((const float4*)x)[i];
    ushort4 h4, l4;
    split_bf16(v.x, h4.x, l4.x);
    split_bf16(v.y, h4.y, l4.y);
    split_bf16(v.z, h4.z, l4.z);
    split_bf16(v.w, h4.w, l4.w);
    ((ushort4*)hi)[i] = h4;
    ((ushort4*)lo)[i] = l4;
}

// both W: [K=256][N=256] f32 -> WT hi/lo bf16 [N][K]; blockIdx<256 -> W1 else W2
__global__ __launch_bounds__(256) void wconv2(const float* __restrict__ W1,
                                              unsigned short* __restrict__ wt1h,
                                              unsigned short* __restrict__ wt1l,
                                              const float* __restrict__ W2,
                                              unsigned short* __restrict__ wt2h,
                                              unsigned short* __restrict__ wt2l) {
    int b = blockIdx.x;
    const float* W = (b < 256) ? W1 : W2;
    unsigned short* wth = (b < 256) ? wt1h : wt2h;
    unsigned short* wtl = (b < 256) ? wt1l : wt2l;
    int t = (b & 255) * 256 + threadIdx.x;           // 0..65535
    int k = t >> 8, n = t & 255;
    unsigned short h, l;
    split_bf16(W[k * 256 + n], h, l);
    wth[n * 256 + k] = h;
    wtl[n * 256 + k] = l;
}

// ---------- split-bf16 MFMA GEMM + fused el/er; output = bf16-hi plane ----------
#define CSTR 261
__global__ __launch_bounds__(256, 2) void gemm_mfma(const unsigned short* __restrict__ Ahi,
                                                    const unsigned short* __restrict__ Alo,
                                                    const unsigned short* __restrict__ WThi,
                                                    const unsigned short* __restrict__ WTlo,
                                                    const float* __restrict__ alv,
                                                    const float* __restrict__ arv,
                                                    unsigned short* __restrict__ fbh,
                                                    float* __restrict__ el,
                                                    float* __restrict__ er) {
    __shared__ char smem[66816];                     // A: 2x32768B; C: 64x261 f32
    const int tid  = threadIdx.x;
    const int lane = tid & 63;
    const int wave = tid >> 6;
    const int block_row = blockIdx.x * 64;

    // ---- stage A tile (hi+lo, 64 rows x 256 k, XOR-swizzled) ----
    const unsigned short* aplane[2] = {Ahi + (size_t)block_row * 256,
                                       Alo + (size_t)block_row * 256};
    #pragma unroll
    for (int i = 0; i < 16; ++i) {
        int chunk = i * 256 + tid;                   // 16B chunks, 0..4095
        int p   = chunk >> 11;
        int row = (chunk >> 5) & 63;
        int c   = chunk & 31;
        uint4 v = *(const uint4*)(aplane[p] + row * 256 + c * 8);
        int off = p * 32768 + row * 512 + ((c * 16) ^ ((row & 7) << 4));
        *(uint4*)(smem + off) = v;
    }
    __syncthreads();

    // ---- K-loop ----
    f32x4 acc[4][4];
    #pragma unroll
    for (int m = 0; m < 4; ++m)
        #pragma unroll
        for (int n = 0; n < 4; ++n)
            acc[m][n] = (f32x4){0, 0, 0, 0};

    const int g = lane >> 4;                         // 0..3
    int arow[4], aswz[4];
    #pragma unroll
    for (int m = 0; m < 4; ++m) {
        int row = m * 16 + (lane & 15);
        arow[m] = row * 512;
        aswz[m] = (row & 7) << 4;
    }
    const unsigned short* wb[2][4];
    #pragma unroll
    for (int n = 0; n < 4; ++n) {
        int col = wave * 64 + n * 16 + (lane & 15);
        wb[0][n] = WThi + col * 256 + g * 8;
        wb[1][n] = WTlo + col * 256 + g * 8;
    }

    #pragma unroll
    for (int t = 0; t < 8; ++t) {
        bf16x8 ah[4], al_[4], wh[4], wl[4];
        int koff = t * 64 + g * 16;
        #pragma unroll
        for (int m = 0; m < 4; ++m) {
            ah[m]  = *(const bf16x8*)(smem + arow[m] + (koff ^ aswz[m]));
            al_[m] = *(const bf16x8*)(smem + 32768 + arow[m] + (koff ^ aswz[m]));
        }
        #pragma unroll
        for (int n = 0; n < 4; ++n) {
            wh[n] = *(const bf16x8*)(wb[0][n] + t * 32);
            wl[n] = *(const bf16x8*)(wb[1][n] + t * 32);
        }
        #pragma unroll
        for (int m = 0; m < 4; ++m)
            #pragma unroll
            for (int n = 0; n < 4; ++n) {
                acc[m][n] = __builtin_amdgcn_mfma_f32_16x16x32_bf16(ah[m],  wh[n], acc[m][n], 0, 0, 0);
                acc[m][n] = __builtin_amdgcn_mfma_f32_16x16x32_bf16(ah[m],  wl[n], acc[m][n], 0, 0, 0);
                acc[m][n] = __builtin_amdgcn_mfma_f32_16x16x32_bf16(al_[m], wh[n], acc[m][n], 0, 0, 0);
            }
    }

    // ---- epilogue: C -> LDS (row-major [64][261]) ----
    __syncthreads();                                 // A planes dead
    float* C = (float*)smem;
    #pragma unroll
    for (int m = 0; m < 4; ++m) {
        int r0 = m * 16 + g * 4;
        #pragma unroll
        for (int n = 0; n < 4; ++n) {
            int col = wave * 64 + n * 16 + (lane & 15);
            C[(r0 + 0) * CSTR + col] = acc[m][n][0];
            C[(r0 + 1) * CSTR + col] = acc[m][n][1];
            C[(r0 + 2) * CSTR + col] = acc[m][n][2];
            C[(r0 + 3) * CSTR + col] = acc[m][n][3];
        }
    }
    __syncthreads();

    // coalesced bf16-hi feat write: 64 rows x 32 chunks of 16B
    #pragma unroll
    for (int i = 0; i < 8; ++i) {
        int flat = i * 256 + tid;                    // 0..2047
        int r  = flat >> 5;
        int c8 = flat & 31;
        const float* cp = C + r * CSTR + c8 * 8;
        unsigned short us[8];
        #pragma unroll
        for (int k = 0; k < 8; ++k) us[k] = f2bf_rn(cp[k]);
        uint4 pk;
        pk.x = (unsigned)us[0] | ((unsigned)us[1] << 16);
        pk.y = (unsigned)us[2] | ((unsigned)us[3] << 16);
        pk.z = (unsigned)us[4] | ((unsigned)us[5] << 16);
        pk.w = (unsigned)us[6] | ((unsigned)us[7] << 16);
        *(uint4*)(fbh + (size_t)(block_row + r) * FDIM + c8 * 8) = pk;
    }

    // fused el/er: thread t -> (head = wave, node = lane)
    int h = wave, node = lane;
    float sl = 0.0f, sr = 0.0f;
    #pragma unroll 8
    for (int d = 0; d < 64; ++d) {
        float v = C[node * CSTR + h * 64 + d];
        sl += v * alv[h * 64 + d];
        sr += v * arv[h * 64 + d];
    }
    el[(block_row + node) * HEADS + h] = sl;
    er[(block_row + node) * HEADS + h] = sr;
}

// ---------- CSR build ----------
__global__ __launch_bounds__(256) void count_deg(const int* __restrict__ dst,
                                                 int* __restrict__ deg) {
    int e = blockIdx.x * 256 + threadIdx.x;
    if (e < NEDGES) atomicAdd(&deg[dst[e]], 1);
}

__global__ __launch_bounds__(256) void scan_block(const int* __restrict__ in,
                                                  int* __restrict__ out,
                                                  int* __restrict__ bsums, int n) {
    int gid = blockIdx.x * 256 + threadIdx.x;
    int v = (gid < n) ? in[gid] : 0;
    int lane = threadIdx.x & 63;
    #pragma unroll
    for (int off = 1; off < 64; off <<= 1) {
        int t = __shfl_up(v, off, 64);
        if (lane >= off) v += t;
    }
    __shared__ int wsum[4];
    int wid = threadIdx.x >> 6;
    if (lane == 63) wsum[wid] = v;
    __syncthreads();
    int add = 0;
    for (int w = 0; w < wid; ++w) add += wsum[w];
    v += add;
    if (gid < n) out[gid] = v;
    if (bsums && threadIdx.x == 255) bsums[blockIdx.x] = v;
}

__global__ __launch_bounds__(256) void scan_add(int* __restrict__ out,
                                                const int* __restrict__ bscan, int n) {
    int gid = blockIdx.x * 256 + threadIdx.x;
    if (blockIdx.x > 0 && gid < n) out[gid] += bscan[blockIdx.x - 1];
}

__global__ __launch_bounds__(256) void fill_csr(const int* __restrict__ src,
                                                const int* __restrict__ dst,
                                                const int* __restrict__ incl,
                                                const int* __restrict__ deg,
                                                int* __restrict__ cursor,
                                                int* __restrict__ csr_src) {
    int e = blockIdx.x * 256 + threadIdx.x;
    if (e >= NEDGES) return;
    int s = src[e], d = dst[e];
    int start = incl[d] - deg[d];
    int pos = start + atomicAdd(&cursor[d], 1);
    csr_src[pos] = s;
}

// ---------- fused per-node softmax + aggregate + bias + ELU ----------
// one 64-lane wave per dst node; 4 waves per block; alpha staged in LDS;
// gather batched 8-deep for memory-level parallelism.
// LAYER==1: write bf16 hi/lo planes; LAYER==2: f32 out [head][node][64]
template <int LAYER>
__global__ __launch_bounds__(256) void gat_node(const int* __restrict__ csr_src,
                                                const int* __restrict__ incl,
                                                const int* __restrict__ deg,
                                                const float* __restrict__ el,
                                                const float* __restrict__ er,
                                                const unsigned short* __restrict__ fbh,
                                                const float* __restrict__ bias,
                                                float* __restrict__ outp,
                                                unsigned short* __restrict__ ohi,
                                                unsigned short* __restrict__ olo) {
    __shared__ float alds[4][64][4];
    __shared__ int   slds[4][64];
    int wv   = threadIdx.x >> 6;
    int node = blockIdx.x * 4 + wv;
    if (node >= NNODES) return;
    int lane = threadIdx.x & 63;
    int h = lane >> 4;

    int end   = incl[node];
    int dg    = deg[node];
    int start = end - dg;
    float4 r4 = ((const float4*)er)[node];
    float4 acc = {0, 0, 0, 0};
    const char* fb = (const char*)fbh;
    const int laneoff = lane * 8;                    // byte offset within 512B row

    if (dg <= 64) {
        // ---- fast path: all scores in registers, single pass ----
        bool act = lane < dg;
        int s = act ? csr_src[start + lane] : 0;
        float4 l4 = ((const float4*)el)[s];
        float c0 = act ? lrelu_f(l4.x + r4.x) : -INFINITY;
        float c1 = act ? lrelu_f(l4.y + r4.y) : -INFINITY;
        float c2 = act ? lrelu_f(l4.z + r4.z) : -INFINITY;
        float c3 = act ? lrelu_f(l4.w + r4.w) : -INFINITY;
        float m0 = c0, m1 = c1, m2 = c2, m3 = c3;
        #pragma unroll
        for (int off = 1; off < 64; off <<= 1) {
            m0 = fmaxf(m0, __shfl_xor(m0, off, 64));
            m1 = fmaxf(m1, __shfl_xor(m1, off, 64));
            m2 = fmaxf(m2, __shfl_xor(m2, off, 64));
            m3 = fmaxf(m3, __shfl_xor(m3, off, 64));
        }
        float p0 = act ? expf(c0 - m0) : 0.0f;
        float p1 = act ? expf(c1 - m1) : 0.0f;
        float p2 = act ? expf(c2 - m2) : 0.0f;
        float p3 = act ? expf(c3 - m3) : 0.0f;
        float s0 = p0, s1 = p1, s2 = p2, s3 = p3;
        #pragma unroll
        for (int off = 1; off < 64; off <<= 1) {
            s0 += __shfl_xor(s0, off, 64);
            s1 += __shfl_xor(s1, off, 64);
            s2 += __shfl_xor(s2, off, 64);
            s3 += __shfl_xor(s3, off, 64);
        }
        float4 a4 = {p0 / s0, p1 / s1, p2 / s2, p3 / s3};
        *(float4*)(&alds[wv][lane][0]) = a4;
        slds[wv][lane] = s;
        __builtin_amdgcn_wave_barrier();
    } else {
        // ---- slow path (deg > 64): two-pass max/denom; alphas spill per chunk below ----
        float m0 = -INFINITY, m1 = -INFINITY, m2 = -INFINITY, m3 = -INFINITY;
        for (int i = start + lane; i < end; i += 64) {
            int s = csr_src[i];
            float4 l4 = ((const float4*)el)[s];
            m0 = fmaxf(m0, lrelu_f(l4.x + r4.x));
            m1 = fmaxf(m1, lrelu_f(l4.y + r4.y));
            m2 = fmaxf(m2, lrelu_f(l4.z + r4.z));
            m3 = fmaxf(m3, lrelu_f(l4.w + r4.w));
        }
        #pragma unroll
        for (int off = 1; off < 64; off <<= 1) {
            m0 = fmaxf(m0, __shfl_xor(m0, off, 64));
            m1 = fmaxf(m1, __shfl_xor(m1, off, 64));
            m2 = fmaxf(m2, __shfl_xor(m2, off, 64));
            m3 = fmaxf(m3, __shfl_xor(m3, off, 64));
        }
        float s0 = 0, s1 = 0, s2 = 0, s3 = 0;
        for (int i = start + lane; i < end; i += 64) {
            int s = csr_src[i];
            float4 l4 = ((const float4*)el)[s];
            s0 += expf(lrelu_f(l4.x + r4.x) - m0);
            s1 += expf(lrelu_f(l4.y + r4.y) - m1);
            s2 += expf(lrelu_f(l4.z + r4.z) - m2);
            s3 += expf(lrelu_f(l4.w + r4.w) - m3);
        }
        #pragma unroll
        for (int off = 1; off < 64; off <<= 1) {
            s0 += __shfl_xor(s0, off, 64);
            s1 += __shfl_xor(s1, off, 64);
            s2 += __shfl_xor(s2, off, 64);
            s3 += __shfl_xor(s3, off, 64);
        }
        float i0 = 1.0f / s0, i1 = 1.0f / s1, i2 = 1.0f / s2, i3 = 1.0f / s3;

        for (int base = start; base < end; base += 64) {
            int cnt = min(64, end - base);
            if (lane < cnt) {
                int s = csr_src[base + lane];
                float4 l4 = ((const float4*)el)[s];
                float4 a4;
                a4.x = expf(lrelu_f(l4.x + r4.x) - m0) * i0;
                a4.y = expf(lrelu_f(l4.y + r4.y) - m1) * i1;
                a4.z = expf(lrelu_f(l4.z + r4.z) - m2) * i2;
                a4.w = expf(lrelu_f(l4.w + r4.w) - m3) * i3;
                *(float4*)(&alds[wv][lane][0]) = a4;
                slds[wv][lane] = s;
            }
            __builtin_amdgcn_wave_barrier();
            for (int j = 0; j < cnt; ++j) {
                float a = alds[wv][j][h];
                int   sj = slds[wv][j];
                uint2 f = *(const uint2*)(fb + ((size_t)sj << 9) + laneoff);
                acc.x += __uint_as_float(f.x << 16) * a;
                acc.y += __uint_as_float(f.x & 0xffff0000u) * a;
                acc.z += __uint_as_float(f.y << 16) * a;
                acc.w += __uint_as_float(f.y & 0xffff0000u) * a;
            }
            __builtin_amdgcn_wave_barrier();
        }
        dg = 0;   // gather already done
    }

    // ---- batched gather (fast path): 8 edges per batch, loads issued together ----
    {
        int nfull = dg & ~7;
        for (int base = 0; base < nfull; base += 8) {
            float aa[8]; int ss[8];
            #pragma unroll
            for (int b = 0; b < 8; ++b) {
                aa[b] = alds[wv][base + b][h];
                ss[b] = slds[wv][base + b];
            }
            uint2 ff[8];
            #pragma unroll
            for (int b = 0; b < 8; ++b)
                ff[b] = *(const uint2*)(fb + ((size_t)ss[b] << 9) + laneoff);
            #pragma unroll
            for (int b = 0; b < 8; ++b) {
                float a = aa[b];
                acc.x += __uint_as_float(ff[b].x << 16) * a;
                acc.y += __uint_as_float(ff[b].x & 0xffff0000u) * a;
                acc.z += __uint_as_float(ff[b].y << 16) * a;
                acc.w += __uint_as_float(ff[b].y & 0xffff0000u) * a;
            }
        }
        for (int j = nfull; j < dg; ++j) {
            float a = alds[wv][j][h];
            int   sj = slds[wv][j];
            uint2 f = *(const uint2*)(fb + ((size_t)sj << 9) + laneoff);
            acc.x += __uint_as_float(f.x << 16) * a;
            acc.y += __uint_as_float(f.x & 0xffff0000u) * a;
            acc.z += __uint_as_float(f.y << 16) * a;
            acc.w += __uint_as_float(f.y & 0xffff0000u) * a;
        }
    }

    float4 b = ((const float4*)bias)[lane];
    acc.x = elu_f(acc.x + b.x);
    acc.y = elu_f(acc.y + b.y);
    acc.z = elu_f(acc.z + b.z);
    acc.w = elu_f(acc.w + b.w);

    if (LAYER == 1) {
        ushort4 h4, l4;
        split_bf16(acc.x, h4.x, l4.x);
        split_bf16(acc.y, h4.y, l4.y);
        split_bf16(acc.z, h4.z, l4.z);
        split_bf16(acc.w, h4.w, l4.w);
        *(ushort4*)(ohi + (size_t)node * FDIM + lane * 4) = h4;
        *(ushort4*)(olo + (size_t)node * FDIM + lane * 4) = l4;
    } else {
        *(float4*)(outp + ((size_t)h * NNODES + node) * HID + (lane & 15) * 4) = acc;
    }
}

// ---------- launch ----------
extern "C" void kernel_launch(void* const* d_in, const int* in_sizes, int n_in,
                              void* d_out, int out_size, void* d_ws, size_t ws_size,
                              hipStream_t stream) {
    const float* x   = (const float*)d_in[0];
    const int*   src = (const int*)d_in[1];
    const int*   dst = (const int*)d_in[2];
    const float* W1  = (const float*)d_in[3];
    const float* al1 = (const float*)d_in[4];
    const float* ar1 = (const float*)d_in[5];
    const float* b1  = (const float*)d_in[6];
    const float* W2  = (const float*)d_in[7];
    const float* al2 = (const float*)d_in[8];
    const float* ar2 = (const float*)d_in[9];
    const float* b2  = (const float*)d_in[10];
    float* out = (float*)d_out;

    unsigned short* fbh  = (unsigned short*)d_ws;                    // NPAD*256 u16
    unsigned short* abhi = fbh  + (size_t)NPAD * FDIM;
    unsigned short* ablo = abhi + (size_t)NPAD * FDIM;
    unsigned short* wt1h = ablo + (size_t)NPAD * FDIM;               // 65536 each
    unsigned short* wt1l = wt1h + 65536;
    unsigned short* wt2h = wt1l + 65536;
    unsigned short* wt2l = wt2h + 65536;
    float* el = (float*)(wt2l + 65536);                              // NPAD*4
    float* er = el + (size_t)NPAD * HEADS;
    int* deg     = (int*)(er + (size_t)NPAD * HEADS);                // deg+cursor adjacent
    int* cursor  = deg + NNODES;
    int* incl    = cursor + NNODES;
    int* aux     = incl + NNODES;
    int* auxs    = aux + 256;
    int* csr_src = auxs + 256;

    const int edge_grid  = (NEDGES + 255) / 256;       // 3125
    const int node_grid  = (NNODES + 255) / 256;       // 196
    const int gat_grid   = (NNODES + 3) / 4;           // 12500
    const int gemm_grid  = NPAD / 64;                  // 782
    const int xconv_grid = (NPAD * 64) / 256;          // 12512

    // ===== converts =====
    wconv2<<<512, 256, 0, stream>>>(W1, wt1h, wt1l, W2, wt2h, wt2l);
    xconv<<<xconv_grid, 256, 0, stream>>>(x, abhi, ablo);

    // ===== CSR build =====
    hipMemsetAsync(deg, 0, 2 * NNODES * sizeof(int), stream);   // deg + cursor
    count_deg<<<edge_grid, 256, 0, stream>>>(dst, deg);
    scan_block<<<node_grid, 256, 0, stream>>>(deg, incl, aux, NNODES);
    scan_block<<<1, 256, 0, stream>>>(aux, auxs, nullptr, node_grid);
    scan_add<<<node_grid, 256, 0, stream>>>(incl, auxs, NNODES);
    fill_csr<<<edge_grid, 256, 0, stream>>>(src, dst, incl, deg, cursor, csr_src);

    // ===== layer 1 =====
    gemm_mfma<<<gemm_grid, 256, 0, stream>>>(abhi, ablo, wt1h, wt1l, al1, ar1, fbh, el, er);
    gat_node<1><<<gat_grid, 256, 0, stream>>>(csr_src, incl, deg, el, er, fbh, b1,
                                              nullptr, abhi, ablo);

    // ===== layer 2 =====
    gemm_mfma<<<gemm_grid, 256, 0, stream>>>(abhi, ablo, wt2h, wt2l, al2, ar2, fbh, el, er);
    gat_node<2><<<gat_grid, 256, 0, stream>>>(csr_src, incl, deg, el, er, fbh, b2,
                                              out, nullptr, nullptr);
}

// Round 6
// 368.357 us; speedup vs baseline: 16.9992x; 1.0022x over previous
//
#include <hip/hip_runtime.h>
#include <cstdint>
#include <cstddef>

#define NNODES 50000
#define NPAD   50048      // 782 * 64
#define NEDGES 800000
#define HEADS 4
#define HID 64
#define FDIM 256          // HEADS*HID == IN_DIM == 256
#define NEG_SLOPE 0.2f

typedef short bf16x8 __attribute__((ext_vector_type(8)));
typedef float f32x4  __attribute__((ext_vector_type(4)));

// ---------- helpers ----------
__device__ __forceinline__ float elu_f(float x) {
    return x > 0.0f ? x : expm1f(x);
}
__device__ __forceinline__ float lrelu_f(float x) {
    return x > 0.0f ? x : NEG_SLOPE * x;
}
__device__ __forceinline__ unsigned short f2bf_rn(float x) {
    unsigned u = __float_as_uint(x);
    unsigned r = u + 0x7FFFu + ((u >> 16) & 1u);
    return (unsigned short)(r >> 16);
}
__device__ __forceinline__ void split_bf16(float x, unsigned short& hi, unsigned short& lo) {
    hi = f2bf_rn(x);
    float fhi = __uint_as_float(((unsigned)hi) << 16);
    lo = f2bf_rn(x - fhi);
}

// ---------- fused prep: wconv (512 blk) + xconv (12512 blk) + count_deg (3125 blk) ----------
#define WCONV_BLKS 512
#define XCONV_BLKS 12512
__global__ __launch_bounds__(256) void prep(const float* __restrict__ x,
                                            unsigned short* __restrict__ abhi,
                                            unsigned short* __restrict__ ablo,
                                            const float* __restrict__ W1,
                                            unsigned short* __restrict__ wt1h,
                                            unsigned short* __restrict__ wt1l,
                                            const float* __restrict__ W2,
                                            unsigned short* __restrict__ wt2h,
                                            unsigned short* __restrict__ wt2l,
                                            const int* __restrict__ dst,
                                            int* __restrict__ deg) {
    int b = blockIdx.x;
    if (b < WCONV_BLKS) {
        const float* W = (b < 256) ? W1 : W2;
        unsigned short* wth = (b < 256) ? wt1h : wt2h;
        unsigned short* wtl = (b < 256) ? wt1l : wt2l;
        int t = (b & 255) * 256 + threadIdx.x;       // 0..65535
        int k = t >> 8, n = t & 255;
        unsigned short h, l;
        split_bf16(W[k * 256 + n], h, l);
        wth[n * 256 + k] = h;
        wtl[n * 256 + k] = l;
    } else if (b < WCONV_BLKS + XCONV_BLKS) {
        int i = (b - WCONV_BLKS) * 256 + threadIdx.x;   // float4 chunk id
        if (i >= NPAD * 64) return;
        int row = i >> 6;
        float4 v = {0, 0, 0, 0};
        if (row < NNODES) v = ((const float4*)x)[i];
        ushort4 h4, l4;
        split_bf16(v.x, h4.x, l4.x);
        split_bf16(v.y, h4.y, l4.y);
        split_bf16(v.z, h4.z, l4.z);
        split_bf16(v.w, h4.w, l4.w);
        ((ushort4*)abhi)[i] = h4;
        ((ushort4*)ablo)[i] = l4;
    } else {
        int e = (b - WCONV_BLKS - XCONV_BLKS) * 256 + threadIdx.x;
        if (e < NEDGES) atomicAdd(&deg[dst[e]], 1);
    }
}

// ---------- split-bf16 MFMA GEMM + fused el/er; output = bf16-hi plane ----------
#define CSTR 261
__global__ __launch_bounds__(256, 2) void gemm_mfma(const unsigned short* __restrict__ Ahi,
                                                    const unsigned short* __restrict__ Alo,
                                                    const unsigned short* __restrict__ WThi,
                                                    const unsigned short* __restrict__ WTlo,
                                                    const float* __restrict__ alv,
                                                    const float* __restrict__ arv,
                                                    unsigned short* __restrict__ fbh,
                                                    float* __restrict__ el,
                                                    float* __restrict__ er) {
    __shared__ char smem[66816];                     // A: 2x32768B; C: 64x261 f32
    const int tid  = threadIdx.x;
    const int lane = tid & 63;
    const int wave = tid >> 6;
    const int block_row = blockIdx.x * 64;

    // ---- stage A tile (hi+lo, 64 rows x 256 k, XOR-swizzled) ----
    const unsigned short* aplane[2] = {Ahi + (size_t)block_row * 256,
                                       Alo + (size_t)block_row * 256};
    #pragma unroll
    for (int i = 0; i < 16; ++i) {
        int chunk = i * 256 + tid;                   // 16B chunks, 0..4095
        int p   = chunk >> 11;
        int row = (chunk >> 5) & 63;
        int c   = chunk & 31;
        uint4 v = *(const uint4*)(aplane[p] + row * 256 + c * 8);
        int off = p * 32768 + row * 512 + ((c * 16) ^ ((row & 7) << 4));
        *(uint4*)(smem + off) = v;
    }
    __syncthreads();

    // ---- K-loop ----
    f32x4 acc[4][4];
    #pragma unroll
    for (int m = 0; m < 4; ++m)
        #pragma unroll
        for (int n = 0; n < 4; ++n)
            acc[m][n] = (f32x4){0, 0, 0, 0};

    const int g = lane >> 4;                         // 0..3
    int arow[4], aswz[4];
    #pragma unroll
    for (int m = 0; m < 4; ++m) {
        int row = m * 16 + (lane & 15);
        arow[m] = row * 512;
        aswz[m] = (row & 7) << 4;
    }
    const unsigned short* wb[2][4];
    #pragma unroll
    for (int n = 0; n < 4; ++n) {
        int col = wave * 64 + n * 16 + (lane & 15);
        wb[0][n] = WThi + col * 256 + g * 8;
        wb[1][n] = WTlo + col * 256 + g * 8;
    }

    #pragma unroll
    for (int t = 0; t < 8; ++t) {
        bf16x8 ah[4], al_[4], wh[4], wl[4];
        int koff = t * 64 + g * 16;
        #pragma unroll
        for (int m = 0; m < 4; ++m) {
            ah[m]  = *(const bf16x8*)(smem + arow[m] + (koff ^ aswz[m]));
            al_[m] = *(const bf16x8*)(smem + 32768 + arow[m] + (koff ^ aswz[m]));
        }
        #pragma unroll
        for (int n = 0; n < 4; ++n) {
            wh[n] = *(const bf16x8*)(wb[0][n] + t * 32);
            wl[n] = *(const bf16x8*)(wb[1][n] + t * 32);
        }
        #pragma unroll
        for (int m = 0; m < 4; ++m)
            #pragma unroll
            for (int n = 0; n < 4; ++n) {
                acc[m][n] = __builtin_amdgcn_mfma_f32_16x16x32_bf16(ah[m],  wh[n], acc[m][n], 0, 0, 0);
                acc[m][n] = __builtin_amdgcn_mfma_f32_16x16x32_bf16(ah[m],  wl[n], acc[m][n], 0, 0, 0);
                acc[m][n] = __builtin_amdgcn_mfma_f32_16x16x32_bf16(al_[m], wh[n], acc[m][n], 0, 0, 0);
            }
    }

    // ---- epilogue: C -> LDS (row-major [64][261]) ----
    __syncthreads();                                 // A planes dead
    float* C = (float*)smem;
    #pragma unroll
    for (int m = 0; m < 4; ++m) {
        int r0 = m * 16 + g * 4;
        #pragma unroll
        for (int n = 0; n < 4; ++n) {
            int col = wave * 64 + n * 16 + (lane & 15);
            C[(r0 + 0) * CSTR + col] = acc[m][n][0];
            C[(r0 + 1) * CSTR + col] = acc[m][n][1];
            C[(r0 + 2) * CSTR + col] = acc[m][n][2];
            C[(r0 + 3) * CSTR + col] = acc[m][n][3];
        }
    }
    __syncthreads();

    // coalesced bf16-hi feat write: 64 rows x 32 chunks of 16B
    #pragma unroll
    for (int i = 0; i < 8; ++i) {
        int flat = i * 256 + tid;                    // 0..2047
        int r  = flat >> 5;
        int c8 = flat & 31;
        const float* cp = C + r * CSTR + c8 * 8;
        unsigned short us[8];
        #pragma unroll
        for (int k = 0; k < 8; ++k) us[k] = f2bf_rn(cp[k]);
        uint4 pk;
        pk.x = (unsigned)us[0] | ((unsigned)us[1] << 16);
        pk.y = (unsigned)us[2] | ((unsigned)us[3] << 16);
        pk.z = (unsigned)us[4] | ((unsigned)us[5] << 16);
        pk.w = (unsigned)us[6] | ((unsigned)us[7] << 16);
        *(uint4*)(fbh + (size_t)(block_row + r) * FDIM + c8 * 8) = pk;
    }

    // fused el/er: thread t -> (head = wave, node = lane)
    int h = wave, node = lane;
    float sl = 0.0f, sr = 0.0f;
    #pragma unroll 8
    for (int d = 0; d < 64; ++d) {
        float v = C[node * CSTR + h * 64 + d];
        sl += v * alv[h * 64 + d];
        sr += v * arv[h * 64 + d];
    }
    el[(block_row + node) * HEADS + h] = sl;
    er[(block_row + node) * HEADS + h] = sr;
}

// ---------- CSR build ----------
__global__ __launch_bounds__(256) void scan_block(const int* __restrict__ in,
                                                  int* __restrict__ out,
                                                  int* __restrict__ bsums, int n) {
    int gid = blockIdx.x * 256 + threadIdx.x;
    int v = (gid < n) ? in[gid] : 0;
    int lane = threadIdx.x & 63;
    #pragma unroll
    for (int off = 1; off < 64; off <<= 1) {
        int t = __shfl_up(v, off, 64);
        if (lane >= off) v += t;
    }
    __shared__ int wsum[4];
    int wid = threadIdx.x >> 6;
    if (lane == 63) wsum[wid] = v;
    __syncthreads();
    int add = 0;
    for (int w = 0; w < wid; ++w) add += wsum[w];
    v += add;
    if (gid < n) out[gid] = v;
    if (bsums && threadIdx.x == 255) bsums[blockIdx.x] = v;
}

__global__ __launch_bounds__(256) void scan_add(int* __restrict__ out,
                                                const int* __restrict__ bscan, int n) {
    int gid = blockIdx.x * 256 + threadIdx.x;
    if (blockIdx.x > 0 && gid < n) out[gid] += bscan[blockIdx.x - 1];
}

__global__ __launch_bounds__(256) void fill_csr(const int* __restrict__ src,
                                                const int* __restrict__ dst,
                                                const int* __restrict__ incl,
                                                const int* __restrict__ deg,
                                                int* __restrict__ cursor,
                                                int* __restrict__ csr_src) {
    int e = blockIdx.x * 256 + threadIdx.x;
    if (e >= NEDGES) return;
    int s = src[e], d = dst[e];
    int start = incl[d] - deg[d];
    int pos = start + atomicAdd(&cursor[d], 1);
    csr_src[pos] = s;
}

// ---------- fused per-node softmax + aggregate + bias + ELU, head-pair split ----------
// one 64-lane wave per (node, head-pair); 4 waves per block = 2 nodes.
// wave handles heads hp*2, hp*2+1; lanes 0-31 -> first head, 32-63 -> second.
// LAYER==1: write bf16 hi/lo planes; LAYER==2: f32 out [head][node][64]
template <int LAYER>
__global__ __launch_bounds__(256, 8) void gat_node(const int* __restrict__ csr_src,
                                                   const int* __restrict__ incl,
                                                   const int* __restrict__ deg,
                                                   const float* __restrict__ el,
                                                   const float* __restrict__ er,
                                                   const unsigned short* __restrict__ fbh,
                                                   const float* __restrict__ bias,
                                                   float* __restrict__ outp,
                                                   unsigned short* __restrict__ ohi,
                                                   unsigned short* __restrict__ olo) {
    __shared__ float alds[4][64][2];
    __shared__ int   slds[4][64];
    int wv   = threadIdx.x >> 6;                 // 0..3
    int node = blockIdx.x * 2 + (wv >> 1);
    int hp   = wv & 1;                           // head-pair
    if (node >= NNODES) return;
    int lane = threadIdx.x & 63;
    int hl   = lane >> 5;                        // head-local 0/1
    int head = hp * 2 + hl;

    int end   = incl[node];
    int dg    = deg[node];
    int start = end - dg;
    float2 r2 = *(const float2*)(er + node * 4 + hp * 2);
    float2 acc = {0, 0};
    const char* fb = (const char*)fbh;
    const int boff = hp * 256 + hl * 128 + (lane & 31) * 4;   // byte off in 512B row

    if (dg <= 64) {
        // ---- fast path: all scores in registers, single pass ----
        bool act = lane < dg;
        int s = act ? csr_src[start + lane] : 0;
        float2 l2 = *(const float2*)(el + s * 4 + hp * 2);
        float c0 = act ? lrelu_f(l2.x + r2.x) : -INFINITY;
        float c1 = act ? lrelu_f(l2.y + r2.y) : -INFINITY;
        float m0 = c0, m1 = c1;
        #pragma unroll
        for (int off = 1; off < 64; off <<= 1) {
            m0 = fmaxf(m0, __shfl_xor(m0, off, 64));
            m1 = fmaxf(m1, __shfl_xor(m1, off, 64));
        }
        float p0 = act ? expf(c0 - m0) : 0.0f;
        float p1 = act ? expf(c1 - m1) : 0.0f;
        float s0 = p0, s1 = p1;
        #pragma unroll
        for (int off = 1; off < 64; off <<= 1) {
            s0 += __shfl_xor(s0, off, 64);
            s1 += __shfl_xor(s1, off, 64);
        }
        alds[wv][lane][0] = p0 / s0;
        alds[wv][lane][1] = p1 / s1;
        slds[wv][lane] = s;
        __builtin_amdgcn_wave_barrier();
    } else {
        // ---- slow path (deg > 64): two-pass max/denom, chunked gather ----
        float m0 = -INFINITY, m1 = -INFINITY;
        for (int i = start + lane; i < end; i += 64) {
            int s = csr_src[i];
            float2 l2 = *(const float2*)(el + s * 4 + hp * 2);
            m0 = fmaxf(m0, lrelu_f(l2.x + r2.x));
            m1 = fmaxf(m1, lrelu_f(l2.y + r2.y));
        }
        #pragma unroll
        for (int off = 1; off < 64; off <<= 1) {
            m0 = fmaxf(m0, __shfl_xor(m0, off, 64));
            m1 = fmaxf(m1, __shfl_xor(m1, off, 64));
        }
        float s0 = 0, s1 = 0;
        for (int i = start + lane; i < end; i += 64) {
            int s = csr_src[i];
            float2 l2 = *(const float2*)(el + s * 4 + hp * 2);
            s0 += expf(lrelu_f(l2.x + r2.x) - m0);
            s1 += expf(lrelu_f(l2.y + r2.y) - m1);
        }
        #pragma unroll
        for (int off = 1; off < 64; off <<= 1) {
            s0 += __shfl_xor(s0, off, 64);
            s1 += __shfl_xor(s1, off, 64);
        }
        float i0 = 1.0f / s0, i1 = 1.0f / s1;

        for (int base = start; base < end; base += 64) {
            int cnt = min(64, end - base);
            if (lane < cnt) {
                int s = csr_src[base + lane];
                float2 l2 = *(const float2*)(el + s * 4 + hp * 2);
                alds[wv][lane][0] = expf(lrelu_f(l2.x + r2.x) - m0) * i0;
                alds[wv][lane][1] = expf(lrelu_f(l2.y + r2.y) - m1) * i1;
                slds[wv][lane] = s;
            }
            __builtin_amdgcn_wave_barrier();
            for (int j = 0; j < cnt; ++j) {
                float a = alds[wv][j][hl];
                int  sj = slds[wv][j];
                unsigned f = *(const unsigned*)(fb + ((size_t)sj << 9) + boff);
                acc.x += __uint_as_float(f << 16) * a;
                acc.y += __uint_as_float(f & 0xffff0000u) * a;
            }
            __builtin_amdgcn_wave_barrier();
        }
        dg = 0;   // gather already done
    }

    // ---- batched gather (fast path): 8 edges per batch ----
    {
        int nfull = dg & ~7;
        for (int base = 0; base < nfull; base += 8) {
            float aa[8]; int ss[8];
            #pragma unroll
            for (int b = 0; b < 8; ++b) {
                aa[b] = alds[wv][base + b][hl];
                ss[b] = slds[wv][base + b];
            }
            unsigned ff[8];
            #pragma unroll
            for (int b = 0; b < 8; ++b)
                ff[b] = *(const unsigned*)(fb + ((size_t)ss[b] << 9) + boff);
            #pragma unroll
            for (int b = 0; b < 8; ++b) {
                acc.x += __uint_as_float(ff[b] << 16) * aa[b];
                acc.y += __uint_as_float(ff[b] & 0xffff0000u) * aa[b];
            }
        }
        for (int j = nfull; j < dg; ++j) {
            float a = alds[wv][j][hl];
            int  sj = slds[wv][j];
            unsigned f = *(const unsigned*)(fb + ((size_t)sj << 9) + boff);
            acc.x += __uint_as_float(f << 16) * a;
            acc.y += __uint_as_float(f & 0xffff0000u) * a;
        }
    }

    float2 bv = *(const float2*)(bias + head * 64 + (lane & 31) * 2);
    acc.x = elu_f(acc.x + bv.x);
    acc.y = elu_f(acc.y + bv.y);

    if (LAYER == 1) {
        ushort2 h2, l2;
        split_bf16(acc.x, h2.x, l2.x);
        split_bf16(acc.y, h2.y, l2.y);
        *(ushort2*)(ohi + (size_t)node * FDIM + head * 64 + (lane & 31) * 2) = h2;
        *(ushort2*)(olo + (size_t)node * FDIM + head * 64 + (lane & 31) * 2) = l2;
    } else {
        *(float2*)(outp + ((size_t)head * NNODES + node) * HID + (lane & 31) * 2) = acc;
    }
}

// ---------- launch ----------
extern "C" void kernel_launch(void* const* d_in, const int* in_sizes, int n_in,
                              void* d_out, int out_size, void* d_ws, size_t ws_size,
                              hipStream_t stream) {
    const float* x   = (const float*)d_in[0];
    const int*   src = (const int*)d_in[1];
    const int*   dst = (const int*)d_in[2];
    const float* W1  = (const float*)d_in[3];
    const float* al1 = (const float*)d_in[4];
    const float* ar1 = (const float*)d_in[5];
    const float* b1  = (const float*)d_in[6];
    const float* W2  = (const float*)d_in[7];
    const float* al2 = (const float*)d_in[8];
    const float* ar2 = (const float*)d_in[9];
    const float* b2  = (const float*)d_in[10];
    float* out = (float*)d_out;

    unsigned short* fbh  = (unsigned short*)d_ws;                    // NPAD*256 u16
    unsigned short* abhi = fbh  + (size_t)NPAD * FDIM;
    unsigned short* ablo = abhi + (size_t)NPAD * FDIM;
    unsigned short* wt1h = ablo + (size_t)NPAD * FDIM;               // 65536 each
    unsigned short* wt1l = wt1h + 65536;
    unsigned short* wt2h = wt1l + 65536;
    unsigned short* wt2l = wt2h + 65536;
    float* el = (float*)(wt2l + 65536);                              // NPAD*4
    float* er = el + (size_t)NPAD * HEADS;
    int* deg     = (int*)(er + (size_t)NPAD * HEADS);                // deg+cursor adjacent
    int* cursor  = deg + NNODES;
    int* incl    = cursor + NNODES;
    int* aux     = incl + NNODES;
    int* auxs    = aux + 256;
    int* csr_src = auxs + 256;

    const int edge_grid  = (NEDGES + 255) / 256;       // 3125
    const int node_grid  = (NNODES + 255) / 256;       // 196
    const int gat_grid   = (NNODES + 1) / 2;           // 25000
    const int gemm_grid  = NPAD / 64;                  // 782
    const int prep_grid  = WCONV_BLKS + XCONV_BLKS + edge_grid;   // 16149

    // ===== prep: weight/x converts + degree count =====
    hipMemsetAsync(deg, 0, 2 * NNODES * sizeof(int), stream);   // deg + cursor
    prep<<<prep_grid, 256, 0, stream>>>(x, abhi, ablo, W1, wt1h, wt1l,
                                        W2, wt2h, wt2l, dst, deg);

    // ===== CSR build =====
    scan_block<<<node_grid, 256, 0, stream>>>(deg, incl, aux, NNODES);
    scan_block<<<1, 256, 0, stream>>>(aux, auxs, nullptr, node_grid);
    scan_add<<<node_grid, 256, 0, stream>>>(incl, auxs, NNODES);
    fill_csr<<<edge_grid, 256, 0, stream>>>(src, dst, incl, deg, cursor, csr_src);

    // ===== layer 1 =====
    gemm_mfma<<<gemm_grid, 256, 0, stream>>>(abhi, ablo, wt1h, wt1l, al1, ar1, fbh, el, er);
    gat_node<1><<<gat_grid, 256, 0, stream>>>(csr_src, incl, deg, el, er, fbh, b1,
                                              nullptr, abhi, ablo);

    // ===== layer 2 =====
    gemm_mfma<<<gemm_grid, 256, 0, stream>>>(abhi, ablo, wt2h, wt2l, al2, ar2, fbh, el, er);
    gat_node<2><<<gat_grid, 256, 0, stream>>>(csr_src, incl, deg, el, er, fbh, b2,
                                              out, nullptr, nullptr);
}